// Round 11
// baseline (195.952 us; speedup 1.0000x reference)
//
#include <hip/hip_runtime.h>
#include <stdint.h>

typedef uint16_t u16;
typedef uint32_t u32;
typedef float    f32x4  __attribute__((ext_vector_type(4)));
typedef short    bf16x8 __attribute__((ext_vector_type(8)));   // 8 bf16 = 4 VGPR
typedef u32      u32x4  __attribute__((ext_vector_type(4)));
typedef u16      u16x8  __attribute__((ext_vector_type(8)));
typedef u16      u16x4  __attribute__((ext_vector_type(4)));

#define MFMA16(a, b, c) __builtin_amdgcn_mfma_f32_16x16x32_bf16((a), (b), (c), 0, 0, 0)

// D_MODEL=1024, D_K=256, B=4, T=4096, rows = B*T = 16384
// scores masked with -1e9 BEFORE /sqrt(d_k)=16 -> fold 1/16 into Q; mask = -1e30 logits (exp->0)
// Round 11 = r10 inner loop (unchanged) + TLP/traffic levers:
//  (a) QBLK=128: 8-wave (512-thr) blocks, same per-wave code; staging per q-row halves;
//      LDS 72KB -> 2 blocks/CU = 16 waves/CU (vs 8); grid 576 ~= 1.1 rounds of 512 slots.
//  (b) XCD swizzle: batch b -> XCDs {2b,2b+1}; one batch's 8MB K/V fits the pair's 8MB L2.
//  (c) cvt_x fused into qkv_gemm (f32 loads + in-reg cvt); cvt_x kernel removed.

__device__ __forceinline__ u16 f2bf(float f) {           // fp32 -> bf16 RNE
  u32 x = __float_as_uint(f);
  return (u16)((x + 0x7FFFu + ((x >> 16) & 1u)) >> 16);
}

// Wt[m][n][k] = W_m[k][n]  (bf16, so GEMM B-frags read contiguous k)
__global__ __launch_bounds__(256) void cvt_w_kernel(const float* __restrict__ Wq,
                                                    const float* __restrict__ Wk,
                                                    const float* __restrict__ Wv,
                                                    u16* __restrict__ Wt) {
  int idx = blockIdx.x * 256 + threadIdx.x;              // < 786432
  int m = idx >> 18;
  int n = (idx >> 10) & 255;
  int k = idx & 1023;
  const float* W = (m == 0) ? Wq : (m == 1) ? Wk : Wv;
  Wt[idx] = f2bf(W[k * 256 + n]);
}

// C = X[16384x1024](f32, cvt in-reg) @ Wt^T + bias. z=0: Q (pre-scaled 1/16), z=1: K,
// z=2: V stored transposed [B][256][4096].
__global__ __launch_bounds__(256) void qkv_gemm_kernel(
    const float* __restrict__ X, const u16* __restrict__ Wt,
    const float* __restrict__ bq, const float* __restrict__ bk, const float* __restrict__ bv,
    u16* __restrict__ Qb, u16* __restrict__ Kb, u16* __restrict__ Vtb) {
  __shared__ __align__(16) char sm[32768];               // Xs [128][64]bf16 @0, Ws [128][64]bf16 @16384
  const int tid = threadIdx.x;
  const int wid = tid >> 6, lane = tid & 63, g = lane >> 4, lr = lane & 15;
  const int wr = wid >> 1, wc = wid & 1;
  const int m0 = blockIdx.x * 128, n0 = blockIdx.y * 128, z = blockIdx.z;
  const u16* W = Wt + z * 262144;

  f32x4 acc[4][4];
#pragma unroll
  for (int mi = 0; mi < 4; ++mi)
#pragma unroll
    for (int ni = 0; ni < 4; ++ni) {
      acc[mi][ni][0] = 0.f; acc[mi][ni][1] = 0.f; acc[mi][ni][2] = 0.f; acc[mi][ni][3] = 0.f;
    }

  for (int k0 = 0; k0 < 1024; k0 += 64) {
    __syncthreads();
#pragma unroll
    for (int r = 0; r < 4; ++r) {
      int ch = r * 256 + tid;
      int row = ch >> 3, c = ch & 7;
      const float* xp = X + (size_t)(m0 + row) * 1024 + k0 + c * 8;   // fused cvt_x
      f32x4 xa = *(const f32x4*)xp;
      f32x4 xb = *(const f32x4*)(xp + 4);
      u16x8 xc;
      xc[0] = f2bf(xa[0]); xc[1] = f2bf(xa[1]); xc[2] = f2bf(xa[2]); xc[3] = f2bf(xa[3]);
      xc[4] = f2bf(xb[0]); xc[5] = f2bf(xb[1]); xc[6] = f2bf(xb[2]); xc[7] = f2bf(xb[3]);
      *(u16x8*)(sm + row * 128 + 16 * (c ^ (row & 7))) = xc;
      u32x4 vw = *(const u32x4*)(W + (size_t)(n0 + row) * 1024 + k0 + c * 8);
      *(u32x4*)(sm + 16384 + row * 128 + 16 * (c ^ (row & 7))) = vw;
    }
    __syncthreads();
#pragma unroll
    for (int kk = 0; kk < 2; ++kk) {
      bf16x8 af[4], bfr[4];
#pragma unroll
      for (int mi = 0; mi < 4; ++mi) {
        int row = wr * 64 + mi * 16 + lr;                // A-frag: lane holds row m=lane&15
        af[mi] = *(const bf16x8*)(sm + row * 128 + 16 * ((kk * 4 + g) ^ (row & 7)));
      }
#pragma unroll
      for (int ni = 0; ni < 4; ++ni) {
        int row = wc * 64 + ni * 16 + lr;                // B-frag: lane holds col n=lane&15
        bfr[ni] = *(const bf16x8*)(sm + 16384 + row * 128 + 16 * ((kk * 4 + g) ^ (row & 7)));
      }
#pragma unroll
      for (int mi = 0; mi < 4; ++mi)
#pragma unroll
        for (int ni = 0; ni < 4; ++ni)
          acc[mi][ni] = MFMA16(af[mi], bfr[ni], acc[mi][ni]);
    }
  }

  const float* bias = (z == 0) ? bq : (z == 1) ? bk : bv;
  if (z < 2) {
    u16* O = (z == 0) ? Qb : Kb;
    const float qscale = (z == 0) ? 0.0625f : 1.0f;      // fold 1/sqrt(256) into Q (exact in bf16)
#pragma unroll
    for (int ni = 0; ni < 4; ++ni) {
      int col = n0 + wc * 64 + ni * 16 + lr;
      float bb = bias[col];
#pragma unroll
      for (int mi = 0; mi < 4; ++mi)
#pragma unroll
        for (int j = 0; j < 4; ++j) {
          int row = m0 + wr * 64 + mi * 16 + 4 * g + j;  // C/D: col=lane&15, row=(lane>>4)*4+j
          O[(size_t)row * 256 + col] = f2bf((acc[mi][ni][j] + bb) * qscale);
        }
    }
  } else {
    // V transposed: stage bf16 tile [col 128][row 128] in LDS, then coalesced 16B stores
    __syncthreads();
#pragma unroll
    for (int ni = 0; ni < 4; ++ni) {
      int cl = wc * 64 + ni * 16 + lr;
      float bb = bias[n0 + cl];
#pragma unroll
      for (int mi = 0; mi < 4; ++mi)
#pragma unroll
        for (int j = 0; j < 4; ++j) {
          int rl = wr * 64 + mi * 16 + 4 * g + j;
          *(u16*)(sm + cl * 256 + rl * 2) = f2bf(acc[mi][ni][j] + bb);
        }
    }
    __syncthreads();
    int bidx = m0 >> 12, tb = m0 & 4095;                 // whole block is one batch (m0 % 128 == 0)
#pragma unroll
    for (int r = 0; r < 8; ++r) {
      int ch = r * 256 + tid;                            // 2048 chunks of 16B: 128 cols x 16 chunks
      int cl = ch >> 4, tp = ch & 15;
      u32x4 v = *(const u32x4*)(sm + cl * 256 + tp * 16);
      *(u32x4*)(Vtb + (size_t)bidx * 1048576 + (size_t)(n0 + cl) * 4096 + tb + tp * 8) = v;
    }
  }
}

// Split-KV flash: QBLK=128, 8 waves (512 thr), swapped-QK^T in-reg softmax, KVBLK=64, T13.
// 1D grid 4*gx with XCD swizzle: xcd=bid&7 -> batch b=xcd>>1, i=(bid>>3)*2+(xcd&1).
// Chunk C = 64<<s cols; qb-group gg = qb>>(s-1) has gg+1 splits; start = gg(gg+1)<<(s-2).
// LDS: K0 @0, K1 @16384 ([32 s][256 d], chunk-swz c^(srow&7));
//      V0 @32768, V1 @49152 ([256 d][32 s], chunk-swz c2^((d>>1)&3)); P @65536, 1KB/wave x8.
__global__ __launch_bounds__(512, 4) void flash_kernel(
    const u16* __restrict__ Qb, const u16* __restrict__ Kb,
    const u16* __restrict__ Vtb, u16* __restrict__ Opart, float2* __restrict__ ML,
    int s, int gx) {
  __shared__ __align__(16) char sm[73728];
  const int tid = threadIdx.x, wid = tid >> 6, lane = tid & 63, g = lane >> 4, lr = lane & 15;
  const int xcd = blockIdx.x & 7;
  const int b = xcd >> 1;                                // batch pinned to XCD pair (L2 locality)
  const int i = ((blockIdx.x >> 3) << 1) + (xcd & 1);    // 0..gx-1, bijective (gx even)
  const int QG = 1 << (s - 1);                           // qbs (of 128 rows) per split-group
  const int NG = 32 >> (s - 1);                          // number of groups (4096/128/QG)
  int g4 = 0;
  while (g4 < NG - 1 && i >= (((g4 + 1) * (g4 + 2)) << (s - 2))) ++g4;
  const int local = i - ((g4 * (g4 + 1)) << (s - 2));
  const int qq = local / (g4 + 1);
  const int sc = local - qq * (g4 + 1);                  // split idx 0..g4
  const int qb = g4 * QG + qq;
  const int t0 = qb * 128;
  const int w0 = t0 + wid * 16;                          // this wave's 16 q-rows
  const int C = 64 << s;
  const int sbase = sc * C;                              // sbase <= t0 by construction

  bf16x8 qf[8];                                          // Q hoisted (already * 1/16); B-frag: col q=lr
  const u16* Qrow = Qb + (size_t)(b * 4096 + w0 + lr) * 256;
#pragma unroll
  for (int kk = 0; kk < 8; ++kk) qf[kk] = *(const bf16x8*)(Qrow + kk * 32 + g * 8);

  f32x4 o[16];                                           // o[n][j]: O[q=lr][dv=n*16+4g+j]
#pragma unroll
  for (int n = 0; n < 16; ++n) { o[n][0] = 0.f; o[n][1] = 0.f; o[n][2] = 0.f; o[n][3] = 0.f; }
  float m_ = -1e30f, l_ = 0.f;                           // per-lane: q-row = w0 + lr

  const u16* Kbase = Kb + (size_t)b * 4096 * 256;
  const u16* Vbase = Vtb + (size_t)b * 1048576;

  const int nto = min(C >> 6, (t0 + 128 - sbase) >> 6);  // OUTER tiles of 64 s-cols (>=1, exact)
  for (int ot = 0; ot < nto; ++ot) {
    const int os0 = sbase + ot * 64;
    __syncthreads();
    // stage K[64][256] + V[256][64] as two 32-col halves (layouts identical to r10)
#pragma unroll
    for (int half = 0; half < 2; ++half) {
      const int sh = os0 + 32 * half;
      char* kb = sm + half * 16384;
      char* vb = sm + 32768 + half * 16384;
#pragma unroll
      for (int rr = 0; rr < 2; ++rr) {
        int ch = rr * 512 + tid;                         // 1024 chunks per half-structure
        int srow = ch >> 5, c = ch & 31;
        u32x4 v = *(const u32x4*)(Kbase + (size_t)(sh + srow) * 256 + c * 8);
        *(u32x4*)(kb + srow * 512 + 16 * (c ^ (srow & 7))) = v;
        int d = ch >> 2, c2 = ch & 3;
        u32x4 v2 = *(const u32x4*)(Vbase + (size_t)d * 4096 + sh + c2 * 8);
        *(u32x4*)(vb + d * 64 + 16 * (c2 ^ ((d >> 1) & 3))) = v2;
      }
    }
    __syncthreads();

#pragma unroll 1
    for (int half = 0; half < 2; ++half) {               // two 32-col sub-tiles, no barrier between
      const int s0 = os0 + 32 * half;
      if (s0 > w0 + 15) break;                           // monotone: later sub-tiles masked too
      const char* kb = sm + half * 16384;
      const char* vb = sm + 32768 + half * 16384;

      // S^T = mfma(K_frag, Q_frag): C col=lane&15 = q (lr), row = 4g+j = s-within-16
      f32x4 sa[2];
#pragma unroll
      for (int ni = 0; ni < 2; ++ni) { sa[ni][0] = 0.f; sa[ni][1] = 0.f; sa[ni][2] = 0.f; sa[ni][3] = 0.f; }
#pragma unroll
      for (int ni = 0; ni < 2; ++ni) {
        int srw = ni * 16 + lr;                          // A-frag: lane holds row s_local = srw
#pragma unroll
        for (int kk = 0; kk < 8; ++kk) {
          bf16x8 kf = *(const bf16x8*)(kb + srw * 512 + 16 * ((kk * 4 + g) ^ (srw & 7)));
          sa[ni] = MFMA16(kf, qf[kk], sa[ni]);           // SWAPPED operands
        }
      }
      const int t = w0 + lr;                             // this lane's q-row
      if (s0 + 31 > w0) {                                // diagonal tile: mask t < s (logits, exp -> 0)
#pragma unroll
        for (int ni = 0; ni < 2; ++ni)
#pragma unroll
          for (int j = 0; j < 4; ++j) {
            int ss = s0 + ni * 16 + 4 * g + j;
            if (t < ss) sa[ni][j] = -1e30f;
          }
      }
      // in-register row softmax; partner lanes at xor 16/32 hold same q-row
      float mt = fmaxf(fmaxf(fmaxf(sa[0][0], sa[0][1]), fmaxf(sa[0][2], sa[0][3])),
                       fmaxf(fmaxf(sa[1][0], sa[1][1]), fmaxf(sa[1][2], sa[1][3])));
      mt = fmaxf(mt, __shfl_xor(mt, 16, 64));
      mt = fmaxf(mt, __shfl_xor(mt, 32, 64));
      // T13 defer-rescale: skip the O-wide rescale unless some row's max grew by > 8
      if (__any(mt > m_ + 8.0f)) {
        float mn = fmaxf(m_, mt);
        float scale = __expf(m_ - mn);
        m_ = mn;
        l_ *= scale;
#pragma unroll
        for (int n = 0; n < 16; ++n)
#pragma unroll
          for (int j = 0; j < 4; ++j) o[n][j] *= scale;
      }
#pragma unroll
      for (int ni = 0; ni < 2; ++ni)
#pragma unroll
        for (int j = 0; j < 4; ++j) sa[ni][j] = __expf(sa[ni][j] - m_);  // bounded by e^8
      float su = (sa[0][0] + sa[0][1]) + (sa[0][2] + sa[0][3]) +
                 (sa[1][0] + sa[1][1]) + (sa[1][2] + sa[1][3]);
      su += __shfl_xor(su, 16, 64);
      su += __shfl_xor(su, 32, 64);
      l_ += su;
      // P^T (bf16) -> per-wave swizzled LDS [q=lr][s chunks of 8], then read back as B-frag
#pragma unroll
      for (int ni = 0; ni < 2; ++ni)
#pragma unroll
        for (int j = 0; j < 4; ++j) {
          int c = ni * 2 + (g >> 1);                     // s = ni*16+4g+j -> chunk c, offset 4(g&1)+j
          *(u16*)(sm + 65536 + wid * 1024 + lr * 64 + 16 * (c ^ (lr & 3)) + (4 * (g & 1) + j) * 2) =
              f2bf(sa[ni][j]);
        }
      asm volatile("s_waitcnt lgkmcnt(0)" ::: "memory"); // cross-lane LDS visibility within wave
      bf16x8 pf = *(const bf16x8*)(sm + 65536 + wid * 1024 + lr * 64 + 16 * (g ^ (lr & 3)));
      // PV: O += mfma(V_frag, P^T_frag): A row dv-within-16, C col = q
#pragma unroll
      for (int n = 0; n < 16; ++n) {
        int d = n * 16 + lr;                             // A-frag: lane holds row dv = d
        bf16x8 vf = *(const bf16x8*)(vb + d * 64 + 16 * (g ^ ((d >> 1) & 3)));
        o[n] = MFMA16(vf, pf, o[n]);
      }
    }
  }

  // write UNNORMALIZED partial O (bf16) + (m,l) at compact slot = b*gx+i, LOCAL rows 0..127
  u16* Orow = Opart + ((size_t)(b * gx + i) * 128 + wid * 16) * 256;
#pragma unroll
  for (int n = 0; n < 16; ++n) {
    u16x4 pk;
    pk[0] = f2bf(o[n][0]); pk[1] = f2bf(o[n][1]); pk[2] = f2bf(o[n][2]); pk[3] = f2bf(o[n][3]);
    *(u16x4*)(Orow + lr * 256 + n * 16 + 4 * g) = pk;
  }
  if (lane < 16) {
    float2 ml; ml.x = m_; ml.y = l_;
    ML[(size_t)(b * gx + i) * 128 + wid * 16 + lane] = ml;
  }
}

// Merge splits: out[b][t][:] = sum_sc exp(m_sc - M) * O_sc / (sum_sc exp(m_sc - M) * l_sc)
__global__ __launch_bounds__(256) void combine_kernel(const u16* __restrict__ Opart,
                                                      const float2* __restrict__ ML,
                                                      float* __restrict__ out,
                                                      int s, int gx) {
  const int wid = threadIdx.x >> 6, lane = threadIdx.x & 63;
  const int rg = blockIdx.x * 4 + wid;                   // 0..16383
  const int b = rg >> 12, t = rg & 4095;
  const int qb = t >> 7;                                 // 128-row slots
  const int gg = qb >> (s - 1), qq = qb & ((1 << (s - 1)) - 1);
  const int n = gg + 1;                                  // valid splits (1..8)
  const size_t base = (size_t)(b * gx) + ((gg * (gg + 1)) << (s - 2)) + qq * (gg + 1);
  const int tl = t & 127;                                // local row within slot
  float mv[8], lv[8], w[8];
  float M = -1e30f;
#pragma unroll
  for (int sc = 0; sc < 8; ++sc)
    if (sc < n) {
      float2 ml = ML[(base + sc) * 128 + tl];
      mv[sc] = ml.x; lv[sc] = ml.y;
      M = fmaxf(M, ml.x);
    }
  float L = 0.f;
#pragma unroll
  for (int sc = 0; sc < 8; ++sc)
    if (sc < n) { w[sc] = __expf(mv[sc] - M); L += w[sc] * lv[sc]; }
  const float inv = 1.0f / L;
  const int c0 = lane * 4;
  float a0 = 0.f, a1 = 0.f, a2 = 0.f, a3 = 0.f;
#pragma unroll
  for (int sc = 0; sc < 8; ++sc)
    if (sc < n) {
      u16x4 v = *(const u16x4*)(Opart + ((base + sc) * 128 + tl) * 256 + c0);
      a0 += w[sc] * __uint_as_float((u32)v[0] << 16);
      a1 += w[sc] * __uint_as_float((u32)v[1] << 16);
      a2 += w[sc] * __uint_as_float((u32)v[2] << 16);
      a3 += w[sc] * __uint_as_float((u32)v[3] << 16);
    }
  f32x4 r; r[0] = a0 * inv; r[1] = a1 * inv; r[2] = a2 * inv; r[3] = a3 * inv;
  *(f32x4*)(out + (size_t)rg * 256 + c0) = r;
}

extern "C" void kernel_launch(void* const* d_in, const int* in_sizes, int n_in,
                              void* d_out, int out_size, void* d_ws, size_t ws_size,
                              hipStream_t stream) {
  const float* X  = (const float*)d_in[0];
  const float* Wq = (const float*)d_in[1];
  const float* bq = (const float*)d_in[2];
  const float* Wk = (const float*)d_in[3];
  const float* bk = (const float*)d_in[4];
  const float* Wv = (const float*)d_in[5];
  const float* bv = (const float*)d_in[6];
  float* out = (float*)d_out;
  char* ws = (char*)d_ws;

  const size_t OFF_WT  = 33554432;                       // [0, OFF_WT) free (was Xb; reused as Opart tier B)
  const size_t OFF_Q   = OFF_WT + 1572864;               // Wt bf16 [3][256][1024]
  const size_t OFF_K   = OFF_Q + 8388608;                // Qb bf16 [16384][256] (pre-scaled 1/16)
  const size_t OFF_VT  = OFF_K + 8388608;                // Kb bf16 [16384][256]
  const size_t PREFIX  = OFF_VT + 8388608;               // Vtb bf16 [4][256][4096]  -> 60293120

  // tier A: s=3, gx=144 (QBLK=128). ML 4*144*128*8 = 589824; Opart 4*144*128*256*2 = 37748736.
  const size_t NEEDED_A = PREFIX + 589824 + 37748736;    // ~94.1 MiB (ws >= 132.7MB proven in r6)
  // tier B: s=4, gx=80. Opart 4*80*128*256*2 = 20971520 overlays dead region @0; ML 327680.
  const size_t NEEDED_B = PREFIX + 327680;               // ~57.8 MiB
  if (ws_size < NEEDED_B) return;                        // defensive: leave poison -> clear failure

  u16* Wt  = (u16*)(ws + OFF_WT);
  u16* Qb  = (u16*)(ws + OFF_Q);
  u16* Kb  = (u16*)(ws + OFF_K);
  u16* Vtb = (u16*)(ws + OFF_VT);

  int s, gx;
  u16* Opart;
  float2* ML;
  if (ws_size >= NEEDED_A) {                             // s=3: chunk 512, <=8 outer tiles/block
    s = 3; gx = 144;
    ML = (float2*)(ws + PREFIX);
    Opart = (u16*)(ws + PREFIX + 589824);
  } else {                                               // s=4: chunk 1024, <=16 outer tiles/block
    s = 4; gx = 80;
    ML = (float2*)(ws + PREFIX);
    Opart = (u16*)ws;                                    // overlays dead [0,21MB) region
  }

  cvt_w_kernel<<<3072, 256, 0, stream>>>(Wq, Wk, Wv, Wt);
  qkv_gemm_kernel<<<dim3(128, 2, 3), 256, 0, stream>>>(X, Wt, bq, bk, bv, Qb, Kb, Vtb);
  flash_kernel<<<4 * gx, 512, 0, stream>>>(Qb, Kb, Vtb, Opart, ML, s, gx);
  combine_kernel<<<4096, 256, 0, stream>>>(Opart, ML, out, s, gx);
}

// Round 12
// 172.223 us; speedup vs baseline: 1.1378x; 1.1378x over previous
//
#include <hip/hip_runtime.h>
#include <stdint.h>

typedef uint16_t u16;
typedef uint32_t u32;
typedef float    f32x4  __attribute__((ext_vector_type(4)));
typedef short    bf16x8 __attribute__((ext_vector_type(8)));   // 8 bf16 = 4 VGPR
typedef u32      u32x4  __attribute__((ext_vector_type(4)));
typedef u16      u16x8  __attribute__((ext_vector_type(8)));
typedef u16      u16x4  __attribute__((ext_vector_type(4)));

#define MFMA16(a, b, c) __builtin_amdgcn_mfma_f32_16x16x32_bf16((a), (b), (c), 0, 0, 0)

// D_MODEL=1024, D_K=256, B=4, T=4096, rows = B*T = 16384
// scores masked with -1e9 BEFORE /sqrt(d_k)=16 -> fold 1/16 into Q; mask = -1e30 logits (exp->0)
// Round 12 = r11 structure, ONE change: __launch_bounds__(512) (no min-waves arg).
// r11 bug: (512,4) forced VGPR to the 64-reg step -> scratch spill (VGPR_Count=64, MfmaUtil down).
// Per-wave state needs ~124 VGPR; with bound removed -> 2 blocks/CU x 8 waves = 16 waves/CU.

__device__ __forceinline__ u16 f2bf(float f) {           // fp32 -> bf16 RNE
  u32 x = __float_as_uint(f);
  return (u16)((x + 0x7FFFu + ((x >> 16) & 1u)) >> 16);
}

// Wt[m][n][k] = W_m[k][n]  (bf16, so GEMM B-frags read contiguous k)
__global__ __launch_bounds__(256) void cvt_w_kernel(const float* __restrict__ Wq,
                                                    const float* __restrict__ Wk,
                                                    const float* __restrict__ Wv,
                                                    u16* __restrict__ Wt) {
  int idx = blockIdx.x * 256 + threadIdx.x;              // < 786432
  int m = idx >> 18;
  int n = (idx >> 10) & 255;
  int k = idx & 1023;
  const float* W = (m == 0) ? Wq : (m == 1) ? Wk : Wv;
  Wt[idx] = f2bf(W[k * 256 + n]);
}

// C = X[16384x1024](f32, cvt in-reg) @ Wt^T + bias. z=0: Q (pre-scaled 1/16), z=1: K,
// z=2: V stored transposed [B][256][4096].
__global__ __launch_bounds__(256) void qkv_gemm_kernel(
    const float* __restrict__ X, const u16* __restrict__ Wt,
    const float* __restrict__ bq, const float* __restrict__ bk, const float* __restrict__ bv,
    u16* __restrict__ Qb, u16* __restrict__ Kb, u16* __restrict__ Vtb) {
  __shared__ __align__(16) char sm[32768];               // Xs [128][64]bf16 @0, Ws [128][64]bf16 @16384
  const int tid = threadIdx.x;
  const int wid = tid >> 6, lane = tid & 63, g = lane >> 4, lr = lane & 15;
  const int wr = wid >> 1, wc = wid & 1;
  const int m0 = blockIdx.x * 128, n0 = blockIdx.y * 128, z = blockIdx.z;
  const u16* W = Wt + z * 262144;

  f32x4 acc[4][4];
#pragma unroll
  for (int mi = 0; mi < 4; ++mi)
#pragma unroll
    for (int ni = 0; ni < 4; ++ni) {
      acc[mi][ni][0] = 0.f; acc[mi][ni][1] = 0.f; acc[mi][ni][2] = 0.f; acc[mi][ni][3] = 0.f;
    }

  for (int k0 = 0; k0 < 1024; k0 += 64) {
    __syncthreads();
#pragma unroll
    for (int r = 0; r < 4; ++r) {
      int ch = r * 256 + tid;
      int row = ch >> 3, c = ch & 7;
      const float* xp = X + (size_t)(m0 + row) * 1024 + k0 + c * 8;   // fused cvt_x
      f32x4 xa = *(const f32x4*)xp;
      f32x4 xb = *(const f32x4*)(xp + 4);
      u16x8 xc;
      xc[0] = f2bf(xa[0]); xc[1] = f2bf(xa[1]); xc[2] = f2bf(xa[2]); xc[3] = f2bf(xa[3]);
      xc[4] = f2bf(xb[0]); xc[5] = f2bf(xb[1]); xc[6] = f2bf(xb[2]); xc[7] = f2bf(xb[3]);
      *(u16x8*)(sm + row * 128 + 16 * (c ^ (row & 7))) = xc;
      u32x4 vw = *(const u32x4*)(W + (size_t)(n0 + row) * 1024 + k0 + c * 8);
      *(u32x4*)(sm + 16384 + row * 128 + 16 * (c ^ (row & 7))) = vw;
    }
    __syncthreads();
#pragma unroll
    for (int kk = 0; kk < 2; ++kk) {
      bf16x8 af[4], bfr[4];
#pragma unroll
      for (int mi = 0; mi < 4; ++mi) {
        int row = wr * 64 + mi * 16 + lr;                // A-frag: lane holds row m=lane&15
        af[mi] = *(const bf16x8*)(sm + row * 128 + 16 * ((kk * 4 + g) ^ (row & 7)));
      }
#pragma unroll
      for (int ni = 0; ni < 4; ++ni) {
        int row = wc * 64 + ni * 16 + lr;                // B-frag: lane holds col n=lane&15
        bfr[ni] = *(const bf16x8*)(sm + 16384 + row * 128 + 16 * ((kk * 4 + g) ^ (row & 7)));
      }
#pragma unroll
      for (int mi = 0; mi < 4; ++mi)
#pragma unroll
        for (int ni = 0; ni < 4; ++ni)
          acc[mi][ni] = MFMA16(af[mi], bfr[ni], acc[mi][ni]);
    }
  }

  const float* bias = (z == 0) ? bq : (z == 1) ? bk : bv;
  if (z < 2) {
    u16* O = (z == 0) ? Qb : Kb;
    const float qscale = (z == 0) ? 0.0625f : 1.0f;      // fold 1/sqrt(256) into Q (exact in bf16)
#pragma unroll
    for (int ni = 0; ni < 4; ++ni) {
      int col = n0 + wc * 64 + ni * 16 + lr;
      float bb = bias[col];
#pragma unroll
      for (int mi = 0; mi < 4; ++mi)
#pragma unroll
        for (int j = 0; j < 4; ++j) {
          int row = m0 + wr * 64 + mi * 16 + 4 * g + j;  // C/D: col=lane&15, row=(lane>>4)*4+j
          O[(size_t)row * 256 + col] = f2bf((acc[mi][ni][j] + bb) * qscale);
        }
    }
  } else {
    // V transposed: stage bf16 tile [col 128][row 128] in LDS, then coalesced 16B stores
    __syncthreads();
#pragma unroll
    for (int ni = 0; ni < 4; ++ni) {
      int cl = wc * 64 + ni * 16 + lr;
      float bb = bias[n0 + cl];
#pragma unroll
      for (int mi = 0; mi < 4; ++mi)
#pragma unroll
        for (int j = 0; j < 4; ++j) {
          int rl = wr * 64 + mi * 16 + 4 * g + j;
          *(u16*)(sm + cl * 256 + rl * 2) = f2bf(acc[mi][ni][j] + bb);
        }
    }
    __syncthreads();
    int bidx = m0 >> 12, tb = m0 & 4095;                 // whole block is one batch (m0 % 128 == 0)
#pragma unroll
    for (int r = 0; r < 8; ++r) {
      int ch = r * 256 + tid;                            // 2048 chunks of 16B: 128 cols x 16 chunks
      int cl = ch >> 4, tp = ch & 15;
      u32x4 v = *(const u32x4*)(sm + cl * 256 + tp * 16);
      *(u32x4*)(Vtb + (size_t)bidx * 1048576 + (size_t)(n0 + cl) * 4096 + tb + tp * 8) = v;
    }
  }
}

// Split-KV flash: QBLK=128, 8 waves (512 thr), swapped-QK^T in-reg softmax, KVBLK=64, T13.
// 1D grid 4*gx with XCD swizzle: xcd=bid&7 -> batch b=xcd>>1, i=(bid>>3)*2+(xcd&1).
// Chunk C = 64<<s cols; qb-group gg = qb>>(s-1) has gg+1 splits; start = gg(gg+1)<<(s-2).
// LDS: K0 @0, K1 @16384 ([32 s][256 d], chunk-swz c^(srow&7));
//      V0 @32768, V1 @49152 ([256 d][32 s], chunk-swz c2^((d>>1)&3)); P @65536, 1KB/wave x8.
__global__ __launch_bounds__(512) void flash_kernel(   // r12: NO min-waves arg (r11 spill bug)
    const u16* __restrict__ Qb, const u16* __restrict__ Kb,
    const u16* __restrict__ Vtb, u16* __restrict__ Opart, float2* __restrict__ ML,
    int s, int gx) {
  __shared__ __align__(16) char sm[73728];
  const int tid = threadIdx.x, wid = tid >> 6, lane = tid & 63, g = lane >> 4, lr = lane & 15;
  const int xcd = blockIdx.x & 7;
  const int b = xcd >> 1;                                // batch pinned to XCD pair (L2 locality)
  const int i = ((blockIdx.x >> 3) << 1) + (xcd & 1);    // 0..gx-1, bijective (gx even)
  const int QG = 1 << (s - 1);                           // qbs (of 128 rows) per split-group
  const int NG = 32 >> (s - 1);                          // number of groups (4096/128/QG)
  int g4 = 0;
  while (g4 < NG - 1 && i >= (((g4 + 1) * (g4 + 2)) << (s - 2))) ++g4;
  const int local = i - ((g4 * (g4 + 1)) << (s - 2));
  const int qq = local / (g4 + 1);
  const int sc = local - qq * (g4 + 1);                  // split idx 0..g4
  const int qb = g4 * QG + qq;
  const int t0 = qb * 128;
  const int w0 = t0 + wid * 16;                          // this wave's 16 q-rows
  const int C = 64 << s;
  const int sbase = sc * C;                              // sbase <= t0 by construction

  bf16x8 qf[8];                                          // Q hoisted (already * 1/16); B-frag: col q=lr
  const u16* Qrow = Qb + (size_t)(b * 4096 + w0 + lr) * 256;
#pragma unroll
  for (int kk = 0; kk < 8; ++kk) qf[kk] = *(const bf16x8*)(Qrow + kk * 32 + g * 8);

  f32x4 o[16];                                           // o[n][j]: O[q=lr][dv=n*16+4g+j]
#pragma unroll
  for (int n = 0; n < 16; ++n) { o[n][0] = 0.f; o[n][1] = 0.f; o[n][2] = 0.f; o[n][3] = 0.f; }
  float m_ = -1e30f, l_ = 0.f;                           // per-lane: q-row = w0 + lr

  const u16* Kbase = Kb + (size_t)b * 4096 * 256;
  const u16* Vbase = Vtb + (size_t)b * 1048576;

  const int nto = min(C >> 6, (t0 + 128 - sbase) >> 6);  // OUTER tiles of 64 s-cols (>=1, exact)
  for (int ot = 0; ot < nto; ++ot) {
    const int os0 = sbase + ot * 64;
    __syncthreads();
    // stage K[64][256] + V[256][64] as two 32-col halves (layouts identical to r10)
#pragma unroll
    for (int half = 0; half < 2; ++half) {
      const int sh = os0 + 32 * half;
      char* kb = sm + half * 16384;
      char* vb = sm + 32768 + half * 16384;
#pragma unroll
      for (int rr = 0; rr < 2; ++rr) {
        int ch = rr * 512 + tid;                         // 1024 chunks per half-structure
        int srow = ch >> 5, c = ch & 31;
        u32x4 v = *(const u32x4*)(Kbase + (size_t)(sh + srow) * 256 + c * 8);
        *(u32x4*)(kb + srow * 512 + 16 * (c ^ (srow & 7))) = v;
        int d = ch >> 2, c2 = ch & 3;
        u32x4 v2 = *(const u32x4*)(Vbase + (size_t)d * 4096 + sh + c2 * 8);
        *(u32x4*)(vb + d * 64 + 16 * (c2 ^ ((d >> 1) & 3))) = v2;
      }
    }
    __syncthreads();

#pragma unroll 1
    for (int half = 0; half < 2; ++half) {               // two 32-col sub-tiles, no barrier between
      const int s0 = os0 + 32 * half;
      if (s0 > w0 + 15) break;                           // monotone: later sub-tiles masked too
      const char* kb = sm + half * 16384;
      const char* vb = sm + 32768 + half * 16384;

      // S^T = mfma(K_frag, Q_frag): C col=lane&15 = q (lr), row = 4g+j = s-within-16
      f32x4 sa[2];
#pragma unroll
      for (int ni = 0; ni < 2; ++ni) { sa[ni][0] = 0.f; sa[ni][1] = 0.f; sa[ni][2] = 0.f; sa[ni][3] = 0.f; }
#pragma unroll
      for (int ni = 0; ni < 2; ++ni) {
        int srw = ni * 16 + lr;                          // A-frag: lane holds row s_local = srw
#pragma unroll
        for (int kk = 0; kk < 8; ++kk) {
          bf16x8 kf = *(const bf16x8*)(kb + srw * 512 + 16 * ((kk * 4 + g) ^ (srw & 7)));
          sa[ni] = MFMA16(kf, qf[kk], sa[ni]);           // SWAPPED operands
        }
      }
      const int t = w0 + lr;                             // this lane's q-row
      if (s0 + 31 > w0) {                                // diagonal tile: mask t < s (logits, exp -> 0)
#pragma unroll
        for (int ni = 0; ni < 2; ++ni)
#pragma unroll
          for (int j = 0; j < 4; ++j) {
            int ss = s0 + ni * 16 + 4 * g + j;
            if (t < ss) sa[ni][j] = -1e30f;
          }
      }
      // in-register row softmax; partner lanes at xor 16/32 hold same q-row
      float mt = fmaxf(fmaxf(fmaxf(sa[0][0], sa[0][1]), fmaxf(sa[0][2], sa[0][3])),
                       fmaxf(fmaxf(sa[1][0], sa[1][1]), fmaxf(sa[1][2], sa[1][3])));
      mt = fmaxf(mt, __shfl_xor(mt, 16, 64));
      mt = fmaxf(mt, __shfl_xor(mt, 32, 64));
      // T13 defer-rescale: skip the O-wide rescale unless some row's max grew by > 8
      if (__any(mt > m_ + 8.0f)) {
        float mn = fmaxf(m_, mt);
        float scale = __expf(m_ - mn);
        m_ = mn;
        l_ *= scale;
#pragma unroll
        for (int n = 0; n < 16; ++n)
#pragma unroll
          for (int j = 0; j < 4; ++j) o[n][j] *= scale;
      }
#pragma unroll
      for (int ni = 0; ni < 2; ++ni)
#pragma unroll
        for (int j = 0; j < 4; ++j) sa[ni][j] = __expf(sa[ni][j] - m_);  // bounded by e^8
      float su = (sa[0][0] + sa[0][1]) + (sa[0][2] + sa[0][3]) +
                 (sa[1][0] + sa[1][1]) + (sa[1][2] + sa[1][3]);
      su += __shfl_xor(su, 16, 64);
      su += __shfl_xor(su, 32, 64);
      l_ += su;
      // P^T (bf16) -> per-wave swizzled LDS [q=lr][s chunks of 8], then read back as B-frag
#pragma unroll
      for (int ni = 0; ni < 2; ++ni)
#pragma unroll
        for (int j = 0; j < 4; ++j) {
          int c = ni * 2 + (g >> 1);                     // s = ni*16+4g+j -> chunk c, offset 4(g&1)+j
          *(u16*)(sm + 65536 + wid * 1024 + lr * 64 + 16 * (c ^ (lr & 3)) + (4 * (g & 1) + j) * 2) =
              f2bf(sa[ni][j]);
        }
      asm volatile("s_waitcnt lgkmcnt(0)" ::: "memory"); // cross-lane LDS visibility within wave
      bf16x8 pf = *(const bf16x8*)(sm + 65536 + wid * 1024 + lr * 64 + 16 * (g ^ (lr & 3)));
      // PV: O += mfma(V_frag, P^T_frag): A row dv-within-16, C col = q
#pragma unroll
      for (int n = 0; n < 16; ++n) {
        int d = n * 16 + lr;                             // A-frag: lane holds row dv = d
        bf16x8 vf = *(const bf16x8*)(vb + d * 64 + 16 * (g ^ ((d >> 1) & 3)));
        o[n] = MFMA16(vf, pf, o[n]);
      }
    }
  }

  // write UNNORMALIZED partial O (bf16) + (m,l) at compact slot = b*gx+i, LOCAL rows 0..127
  u16* Orow = Opart + ((size_t)(b * gx + i) * 128 + wid * 16) * 256;
#pragma unroll
  for (int n = 0; n < 16; ++n) {
    u16x4 pk;
    pk[0] = f2bf(o[n][0]); pk[1] = f2bf(o[n][1]); pk[2] = f2bf(o[n][2]); pk[3] = f2bf(o[n][3]);
    *(u16x4*)(Orow + lr * 256 + n * 16 + 4 * g) = pk;
  }
  if (lane < 16) {
    float2 ml; ml.x = m_; ml.y = l_;
    ML[(size_t)(b * gx + i) * 128 + wid * 16 + lane] = ml;
  }
}

// Merge splits: out[b][t][:] = sum_sc exp(m_sc - M) * O_sc / (sum_sc exp(m_sc - M) * l_sc)
__global__ __launch_bounds__(256) void combine_kernel(const u16* __restrict__ Opart,
                                                      const float2* __restrict__ ML,
                                                      float* __restrict__ out,
                                                      int s, int gx) {
  const int wid = threadIdx.x >> 6, lane = threadIdx.x & 63;
  const int rg = blockIdx.x * 4 + wid;                   // 0..16383
  const int b = rg >> 12, t = rg & 4095;
  const int qb = t >> 7;                                 // 128-row slots
  const int gg = qb >> (s - 1), qq = qb & ((1 << (s - 1)) - 1);
  const int n = gg + 1;                                  // valid splits (1..8)
  const size_t base = (size_t)(b * gx) + ((gg * (gg + 1)) << (s - 2)) + qq * (gg + 1);
  const int tl = t & 127;                                // local row within slot
  float mv[8], lv[8], w[8];
  float M = -1e30f;
#pragma unroll
  for (int sc = 0; sc < 8; ++sc)
    if (sc < n) {
      float2 ml = ML[(base + sc) * 128 + tl];
      mv[sc] = ml.x; lv[sc] = ml.y;
      M = fmaxf(M, ml.x);
    }
  float L = 0.f;
#pragma unroll
  for (int sc = 0; sc < 8; ++sc)
    if (sc < n) { w[sc] = __expf(mv[sc] - M); L += w[sc] * lv[sc]; }
  const float inv = 1.0f / L;
  const int c0 = lane * 4;
  float a0 = 0.f, a1 = 0.f, a2 = 0.f, a3 = 0.f;
#pragma unroll
  for (int sc = 0; sc < 8; ++sc)
    if (sc < n) {
      u16x4 v = *(const u16x4*)(Opart + ((base + sc) * 128 + tl) * 256 + c0);
      a0 += w[sc] * __uint_as_float((u32)v[0] << 16);
      a1 += w[sc] * __uint_as_float((u32)v[1] << 16);
      a2 += w[sc] * __uint_as_float((u32)v[2] << 16);
      a3 += w[sc] * __uint_as_float((u32)v[3] << 16);
    }
  f32x4 r; r[0] = a0 * inv; r[1] = a1 * inv; r[2] = a2 * inv; r[3] = a3 * inv;
  *(f32x4*)(out + (size_t)rg * 256 + c0) = r;
}

extern "C" void kernel_launch(void* const* d_in, const int* in_sizes, int n_in,
                              void* d_out, int out_size, void* d_ws, size_t ws_size,
                              hipStream_t stream) {
  const float* X  = (const float*)d_in[0];
  const float* Wq = (const float*)d_in[1];
  const float* bq = (const float*)d_in[2];
  const float* Wk = (const float*)d_in[3];
  const float* bk = (const float*)d_in[4];
  const float* Wv = (const float*)d_in[5];
  const float* bv = (const float*)d_in[6];
  float* out = (float*)d_out;
  char* ws = (char*)d_ws;

  const size_t OFF_WT  = 33554432;                       // [0, OFF_WT) free (reused as Opart tier B)
  const size_t OFF_Q   = OFF_WT + 1572864;               // Wt bf16 [3][256][1024]
  const size_t OFF_K   = OFF_Q + 8388608;                // Qb bf16 [16384][256] (pre-scaled 1/16)
  const size_t OFF_VT  = OFF_K + 8388608;                // Kb bf16 [16384][256]
  const size_t PREFIX  = OFF_VT + 8388608;               // Vtb bf16 [4][256][4096]  -> 60293120

  // tier A: s=3, gx=144 (QBLK=128). ML 4*144*128*8 = 589824; Opart 4*144*128*256*2 = 37748736.
  const size_t NEEDED_A = PREFIX + 589824 + 37748736;    // ~94.1 MiB (ws >= 132.7MB proven in r6)
  // tier B: s=4, gx=80. Opart 4*80*128*256*2 = 20971520 overlays dead region @0; ML 327680.
  const size_t NEEDED_B = PREFIX + 327680;               // ~57.8 MiB
  if (ws_size < NEEDED_B) return;                        // defensive: leave poison -> clear failure

  u16* Wt  = (u16*)(ws + OFF_WT);
  u16* Qb  = (u16*)(ws + OFF_Q);
  u16* Kb  = (u16*)(ws + OFF_K);
  u16* Vtb = (u16*)(ws + OFF_VT);

  int s, gx;
  u16* Opart;
  float2* ML;
  if (ws_size >= NEEDED_A) {                             // s=3: chunk 512, <=8 outer tiles/block
    s = 3; gx = 144;
    ML = (float2*)(ws + PREFIX);
    Opart = (u16*)(ws + PREFIX + 589824);
  } else {                                               // s=4: chunk 1024, <=16 outer tiles/block
    s = 4; gx = 80;
    ML = (float2*)(ws + PREFIX);
    Opart = (u16*)ws;                                    // overlays dead [0,21MB) region
  }

  cvt_w_kernel<<<3072, 256, 0, stream>>>(Wq, Wk, Wv, Wt);
  qkv_gemm_kernel<<<dim3(128, 2, 3), 256, 0, stream>>>(X, Wt, bq, bk, bv, Qb, Kb, Vtb);
  flash_kernel<<<4 * gx, 512, 0, stream>>>(Qb, Kb, Vtb, Opart, ML, s, gx);
  combine_kernel<<<4096, 256, 0, stream>>>(Opart, ML, out, s, gx);
}

// Round 13
// 168.088 us; speedup vs baseline: 1.1658x; 1.0246x over previous
//
#include <hip/hip_runtime.h>
#include <stdint.h>

typedef uint16_t u16;
typedef uint32_t u32;
typedef float    f32x4  __attribute__((ext_vector_type(4)));
typedef short    bf16x8 __attribute__((ext_vector_type(8)));   // 8 bf16 = 4 VGPR
typedef u32      u32x4  __attribute__((ext_vector_type(4)));
typedef u16      u16x8  __attribute__((ext_vector_type(8)));
typedef u16      u16x4  __attribute__((ext_vector_type(4)));

#define MFMA16(a, b, c) __builtin_amdgcn_mfma_f32_16x16x32_bf16((a), (b), (c), 0, 0, 0)

// D_MODEL=1024, D_K=256, B=4, T=4096, rows = B*T = 16384
// scores masked with -1e9 BEFORE /sqrt(d_k)=16 -> fold 1/16 into Q; mask = -1e30 logits (exp->0)
// Round 13 = r12 (105us flash) + T14 async-stage: next outer tile's K/V held in 32 staging VGPRs,
// global loads issued right after current tile's reg->LDS writes -> load latency hidden under
// ~2 sub-tile computes; only ds_writes remain between barriers. r9's T14 failure was the 128-VGPR
// cliff (132 regs @ 4-wave step), not the mechanism: here 84+32 ~= 116 stays under 128.

__device__ __forceinline__ u16 f2bf(float f) {           // fp32 -> bf16 RNE
  u32 x = __float_as_uint(f);
  return (u16)((x + 0x7FFFu + ((x >> 16) & 1u)) >> 16);
}

// Wt[m][n][k] = W_m[k][n]  (bf16, so GEMM B-frags read contiguous k)
__global__ __launch_bounds__(256) void cvt_w_kernel(const float* __restrict__ Wq,
                                                    const float* __restrict__ Wk,
                                                    const float* __restrict__ Wv,
                                                    u16* __restrict__ Wt) {
  int idx = blockIdx.x * 256 + threadIdx.x;              // < 786432
  int m = idx >> 18;
  int n = (idx >> 10) & 255;
  int k = idx & 1023;
  const float* W = (m == 0) ? Wq : (m == 1) ? Wk : Wv;
  Wt[idx] = f2bf(W[k * 256 + n]);
}

// C = X[16384x1024](f32, cvt in-reg) @ Wt^T + bias. z=0: Q (pre-scaled 1/16), z=1: K,
// z=2: V stored transposed [B][256][4096].
__global__ __launch_bounds__(256) void qkv_gemm_kernel(
    const float* __restrict__ X, const u16* __restrict__ Wt,
    const float* __restrict__ bq, const float* __restrict__ bk, const float* __restrict__ bv,
    u16* __restrict__ Qb, u16* __restrict__ Kb, u16* __restrict__ Vtb) {
  __shared__ __align__(16) char sm[32768];               // Xs [128][64]bf16 @0, Ws [128][64]bf16 @16384
  const int tid = threadIdx.x;
  const int wid = tid >> 6, lane = tid & 63, g = lane >> 4, lr = lane & 15;
  const int wr = wid >> 1, wc = wid & 1;
  const int m0 = blockIdx.x * 128, n0 = blockIdx.y * 128, z = blockIdx.z;
  const u16* W = Wt + z * 262144;

  f32x4 acc[4][4];
#pragma unroll
  for (int mi = 0; mi < 4; ++mi)
#pragma unroll
    for (int ni = 0; ni < 4; ++ni) {
      acc[mi][ni][0] = 0.f; acc[mi][ni][1] = 0.f; acc[mi][ni][2] = 0.f; acc[mi][ni][3] = 0.f;
    }

  for (int k0 = 0; k0 < 1024; k0 += 64) {
    __syncthreads();
#pragma unroll
    for (int r = 0; r < 4; ++r) {
      int ch = r * 256 + tid;
      int row = ch >> 3, c = ch & 7;
      const float* xp = X + (size_t)(m0 + row) * 1024 + k0 + c * 8;   // fused cvt_x
      f32x4 xa = *(const f32x4*)xp;
      f32x4 xb = *(const f32x4*)(xp + 4);
      u16x8 xc;
      xc[0] = f2bf(xa[0]); xc[1] = f2bf(xa[1]); xc[2] = f2bf(xa[2]); xc[3] = f2bf(xa[3]);
      xc[4] = f2bf(xb[0]); xc[5] = f2bf(xb[1]); xc[6] = f2bf(xb[2]); xc[7] = f2bf(xb[3]);
      *(u16x8*)(sm + row * 128 + 16 * (c ^ (row & 7))) = xc;
      u32x4 vw = *(const u32x4*)(W + (size_t)(n0 + row) * 1024 + k0 + c * 8);
      *(u32x4*)(sm + 16384 + row * 128 + 16 * (c ^ (row & 7))) = vw;
    }
    __syncthreads();
#pragma unroll
    for (int kk = 0; kk < 2; ++kk) {
      bf16x8 af[4], bfr[4];
#pragma unroll
      for (int mi = 0; mi < 4; ++mi) {
        int row = wr * 64 + mi * 16 + lr;                // A-frag: lane holds row m=lane&15
        af[mi] = *(const bf16x8*)(sm + row * 128 + 16 * ((kk * 4 + g) ^ (row & 7)));
      }
#pragma unroll
      for (int ni = 0; ni < 4; ++ni) {
        int row = wc * 64 + ni * 16 + lr;                // B-frag: lane holds col n=lane&15
        bfr[ni] = *(const bf16x8*)(sm + 16384 + row * 128 + 16 * ((kk * 4 + g) ^ (row & 7)));
      }
#pragma unroll
      for (int mi = 0; mi < 4; ++mi)
#pragma unroll
        for (int ni = 0; ni < 4; ++ni)
          acc[mi][ni] = MFMA16(af[mi], bfr[ni], acc[mi][ni]);
    }
  }

  const float* bias = (z == 0) ? bq : (z == 1) ? bk : bv;
  if (z < 2) {
    u16* O = (z == 0) ? Qb : Kb;
    const float qscale = (z == 0) ? 0.0625f : 1.0f;      // fold 1/sqrt(256) into Q (exact in bf16)
#pragma unroll
    for (int ni = 0; ni < 4; ++ni) {
      int col = n0 + wc * 64 + ni * 16 + lr;
      float bb = bias[col];
#pragma unroll
      for (int mi = 0; mi < 4; ++mi)
#pragma unroll
        for (int j = 0; j < 4; ++j) {
          int row = m0 + wr * 64 + mi * 16 + 4 * g + j;  // C/D: col=lane&15, row=(lane>>4)*4+j
          O[(size_t)row * 256 + col] = f2bf((acc[mi][ni][j] + bb) * qscale);
        }
    }
  } else {
    // V transposed: stage bf16 tile [col 128][row 128] in LDS, then coalesced 16B stores
    __syncthreads();
#pragma unroll
    for (int ni = 0; ni < 4; ++ni) {
      int cl = wc * 64 + ni * 16 + lr;
      float bb = bias[n0 + cl];
#pragma unroll
      for (int mi = 0; mi < 4; ++mi)
#pragma unroll
        for (int j = 0; j < 4; ++j) {
          int rl = wr * 64 + mi * 16 + 4 * g + j;
          *(u16*)(sm + cl * 256 + rl * 2) = f2bf(acc[mi][ni][j] + bb);
        }
    }
    __syncthreads();
    int bidx = m0 >> 12, tb = m0 & 4095;                 // whole block is one batch (m0 % 128 == 0)
#pragma unroll
    for (int r = 0; r < 8; ++r) {
      int ch = r * 256 + tid;                            // 2048 chunks of 16B: 128 cols x 16 chunks
      int cl = ch >> 4, tp = ch & 15;
      u32x4 v = *(const u32x4*)(sm + cl * 256 + tp * 16);
      *(u32x4*)(Vtb + (size_t)bidx * 1048576 + (size_t)(n0 + cl) * 4096 + tb + tp * 8) = v;
    }
  }
}

// Split-KV flash: QBLK=128, 8 waves (512 thr), swapped-QK^T in-reg softmax, KVBLK=64, T13, T14.
// 1D grid 4*gx with XCD swizzle: xcd=bid&7 -> batch b=xcd>>1, i=(bid>>3)*2+(xcd&1).
// Chunk C = 64<<s cols; qb-group gg = qb>>(s-1) has gg+1 splits; start = gg(gg+1)<<(s-2).
// LDS: K0 @0, K1 @16384 ([32 s][256 d], chunk-swz c^(srow&7));
//      V0 @32768, V1 @49152 ([256 d][32 s], chunk-swz c2^((d>>1)&3)); P @65536, 1KB/wave x8.
__global__ __launch_bounds__(512) void flash_kernel(
    const u16* __restrict__ Qb, const u16* __restrict__ Kb,
    const u16* __restrict__ Vtb, u16* __restrict__ Opart, float2* __restrict__ ML,
    int s, int gx) {
  __shared__ __align__(16) char sm[73728];
  const int tid = threadIdx.x, wid = tid >> 6, lane = tid & 63, g = lane >> 4, lr = lane & 15;
  const int xcd = blockIdx.x & 7;
  const int b = xcd >> 1;                                // batch pinned to XCD pair (L2 locality)
  const int i = ((blockIdx.x >> 3) << 1) + (xcd & 1);    // 0..gx-1, bijective (gx even)
  const int QG = 1 << (s - 1);                           // qbs (of 128 rows) per split-group
  const int NG = 32 >> (s - 1);                          // number of groups (4096/128/QG)
  int g4 = 0;
  while (g4 < NG - 1 && i >= (((g4 + 1) * (g4 + 2)) << (s - 2))) ++g4;
  const int local = i - ((g4 * (g4 + 1)) << (s - 2));
  const int qq = local / (g4 + 1);
  const int sc = local - qq * (g4 + 1);                  // split idx 0..g4
  const int qb = g4 * QG + qq;
  const int t0 = qb * 128;
  const int w0 = t0 + wid * 16;                          // this wave's 16 q-rows
  const int C = 64 << s;
  const int sbase = sc * C;                              // sbase <= t0 by construction

  bf16x8 qf[8];                                          // Q hoisted (already * 1/16); B-frag: col q=lr
  const u16* Qrow = Qb + (size_t)(b * 4096 + w0 + lr) * 256;
#pragma unroll
  for (int kk = 0; kk < 8; ++kk) qf[kk] = *(const bf16x8*)(Qrow + kk * 32 + g * 8);

  f32x4 o[16];                                           // o[n][j]: O[q=lr][dv=n*16+4g+j]
#pragma unroll
  for (int n = 0; n < 16; ++n) { o[n][0] = 0.f; o[n][1] = 0.f; o[n][2] = 0.f; o[n][3] = 0.f; }
  float m_ = -1e30f, l_ = 0.f;                           // per-lane: q-row = w0 + lr

  const u16* Kbase = Kb + (size_t)b * 4096 * 256;
  const u16* Vbase = Vtb + (size_t)b * 1048576;

  // T14 staging registers: next outer tile (K 64x256 + V 256x64) = 4+4 chunks of 16B per thread
  u32x4 pk[4], pv[4];
#define LOADTILE(os_)                                                                      \
  {                                                                                        \
    _Pragma("unroll")                                                                      \
    for (int q = 0; q < 4; ++q) {                                                          \
      int half = q >> 1, rr = q & 1;                                                       \
      int ch = rr * 512 + tid;                       /* 0..1023 within half-structure */   \
      int srow = ch >> 5, c = ch & 31;                                                     \
      pk[q] = *(const u32x4*)(Kbase + (size_t)((os_) + half * 32 + srow) * 256 + c * 8);   \
      int d = ch >> 2, c2 = ch & 3;                                                        \
      pv[q] = *(const u32x4*)(Vbase + (size_t)d * 4096 + (os_) + half * 32 + c2 * 8);      \
    }                                                                                      \
  }

  const int nto = min(C >> 6, (t0 + 128 - sbase) >> 6);  // OUTER tiles of 64 s-cols (>=1, exact)
  LOADTILE(sbase);                                       // prologue: tile 0 -> regs

  for (int ot = 0; ot < nto; ++ot) {
    const int os0 = sbase + ot * 64;
    __syncthreads();                                     // previous compute done -> LDS writable
#pragma unroll
    for (int q = 0; q < 4; ++q) {                        // reg -> LDS (layouts identical to r12)
      int half = q >> 1, rr = q & 1;
      int ch = rr * 512 + tid;
      int srow = ch >> 5, c = ch & 31;
      *(u32x4*)(sm + half * 16384 + srow * 512 + 16 * (c ^ (srow & 7))) = pk[q];
      int d = ch >> 2, c2 = ch & 3;
      *(u32x4*)(sm + 32768 + half * 16384 + d * 64 + 16 * (c2 ^ ((d >> 1) & 3))) = pv[q];
    }
    if (ot + 1 < nto) LOADTILE(os0 + 64);                // issue next tile; lands during compute
    __syncthreads();                                     // LDS ready

#pragma unroll 1
    for (int half = 0; half < 2; ++half) {               // two 32-col sub-tiles, no barrier between
      const int s0 = os0 + 32 * half;
      if (s0 > w0 + 15) break;                           // monotone: later sub-tiles masked too
      const char* kb = sm + half * 16384;
      const char* vb = sm + 32768 + half * 16384;

      // S^T = mfma(K_frag, Q_frag): C col=lane&15 = q (lr), row = 4g+j = s-within-16
      f32x4 sa[2];
#pragma unroll
      for (int ni = 0; ni < 2; ++ni) { sa[ni][0] = 0.f; sa[ni][1] = 0.f; sa[ni][2] = 0.f; sa[ni][3] = 0.f; }
#pragma unroll
      for (int ni = 0; ni < 2; ++ni) {
        int srw = ni * 16 + lr;                          // A-frag: lane holds row s_local = srw
#pragma unroll
        for (int kk = 0; kk < 8; ++kk) {
          bf16x8 kf = *(const bf16x8*)(kb + srw * 512 + 16 * ((kk * 4 + g) ^ (srw & 7)));
          sa[ni] = MFMA16(kf, qf[kk], sa[ni]);           // SWAPPED operands
        }
      }
      const int t = w0 + lr;                             // this lane's q-row
      if (s0 + 31 > w0) {                                // diagonal tile: mask t < s (logits, exp -> 0)
#pragma unroll
        for (int ni = 0; ni < 2; ++ni)
#pragma unroll
          for (int j = 0; j < 4; ++j) {
            int ss = s0 + ni * 16 + 4 * g + j;
            if (t < ss) sa[ni][j] = -1e30f;
          }
      }
      // in-register row softmax; partner lanes at xor 16/32 hold same q-row
      float mt = fmaxf(fmaxf(fmaxf(sa[0][0], sa[0][1]), fmaxf(sa[0][2], sa[0][3])),
                       fmaxf(fmaxf(sa[1][0], sa[1][1]), fmaxf(sa[1][2], sa[1][3])));
      mt = fmaxf(mt, __shfl_xor(mt, 16, 64));
      mt = fmaxf(mt, __shfl_xor(mt, 32, 64));
      // T13 defer-rescale: skip the O-wide rescale unless some row's max grew by > 8
      if (__any(mt > m_ + 8.0f)) {
        float mn = fmaxf(m_, mt);
        float scale = __expf(m_ - mn);
        m_ = mn;
        l_ *= scale;
#pragma unroll
        for (int n = 0; n < 16; ++n)
#pragma unroll
          for (int j = 0; j < 4; ++j) o[n][j] *= scale;
      }
#pragma unroll
      for (int ni = 0; ni < 2; ++ni)
#pragma unroll
        for (int j = 0; j < 4; ++j) sa[ni][j] = __expf(sa[ni][j] - m_);  // bounded by e^8
      float su = (sa[0][0] + sa[0][1]) + (sa[0][2] + sa[0][3]) +
                 (sa[1][0] + sa[1][1]) + (sa[1][2] + sa[1][3]);
      su += __shfl_xor(su, 16, 64);
      su += __shfl_xor(su, 32, 64);
      l_ += su;
      // P^T (bf16) -> per-wave swizzled LDS [q=lr][s chunks of 8], then read back as B-frag
#pragma unroll
      for (int ni = 0; ni < 2; ++ni)
#pragma unroll
        for (int j = 0; j < 4; ++j) {
          int c = ni * 2 + (g >> 1);                     // s = ni*16+4g+j -> chunk c, offset 4(g&1)+j
          *(u16*)(sm + 65536 + wid * 1024 + lr * 64 + 16 * (c ^ (lr & 3)) + (4 * (g & 1) + j) * 2) =
              f2bf(sa[ni][j]);
        }
      asm volatile("s_waitcnt lgkmcnt(0)" ::: "memory"); // cross-lane LDS visibility within wave
      bf16x8 pf = *(const bf16x8*)(sm + 65536 + wid * 1024 + lr * 64 + 16 * (g ^ (lr & 3)));
      // PV: O += mfma(V_frag, P^T_frag): A row dv-within-16, C col = q
#pragma unroll
      for (int n = 0; n < 16; ++n) {
        int d = n * 16 + lr;                             // A-frag: lane holds row dv = d
        bf16x8 vf = *(const bf16x8*)(vb + d * 64 + 16 * (g ^ ((d >> 1) & 3)));
        o[n] = MFMA16(vf, pf, o[n]);
      }
    }
  }
#undef LOADTILE

  // write UNNORMALIZED partial O (bf16) + (m,l) at compact slot = b*gx+i, LOCAL rows 0..127
  u16* Orow = Opart + ((size_t)(b * gx + i) * 128 + wid * 16) * 256;
#pragma unroll
  for (int n = 0; n < 16; ++n) {
    u16x4 pkk;
    pkk[0] = f2bf(o[n][0]); pkk[1] = f2bf(o[n][1]); pkk[2] = f2bf(o[n][2]); pkk[3] = f2bf(o[n][3]);
    *(u16x4*)(Orow + lr * 256 + n * 16 + 4 * g) = pkk;
  }
  if (lane < 16) {
    float2 ml; ml.x = m_; ml.y = l_;
    ML[(size_t)(b * gx + i) * 128 + wid * 16 + lane] = ml;
  }
}

// Merge splits: out[b][t][:] = sum_sc exp(m_sc - M) * O_sc / (sum_sc exp(m_sc - M) * l_sc)
__global__ __launch_bounds__(256) void combine_kernel(const u16* __restrict__ Opart,
                                                      const float2* __restrict__ ML,
                                                      float* __restrict__ out,
                                                      int s, int gx) {
  const int wid = threadIdx.x >> 6, lane = threadIdx.x & 63;
  const int rg = blockIdx.x * 4 + wid;                   // 0..16383
  const int b = rg >> 12, t = rg & 4095;
  const int qb = t >> 7;                                 // 128-row slots
  const int gg = qb >> (s - 1), qq = qb & ((1 << (s - 1)) - 1);
  const int n = gg + 1;                                  // valid splits (1..8)
  const size_t base = (size_t)(b * gx) + ((gg * (gg + 1)) << (s - 2)) + qq * (gg + 1);
  const int tl = t & 127;                                // local row within slot
  float mv[8], lv[8], w[8];
  float M = -1e30f;
#pragma unroll
  for (int sc = 0; sc < 8; ++sc)
    if (sc < n) {
      float2 ml = ML[(base + sc) * 128 + tl];
      mv[sc] = ml.x; lv[sc] = ml.y;
      M = fmaxf(M, ml.x);
    }
  float L = 0.f;
#pragma unroll
  for (int sc = 0; sc < 8; ++sc)
    if (sc < n) { w[sc] = __expf(mv[sc] - M); L += w[sc] * lv[sc]; }
  const float inv = 1.0f / L;
  const int c0 = lane * 4;
  float a0 = 0.f, a1 = 0.f, a2 = 0.f, a3 = 0.f;
#pragma unroll
  for (int sc = 0; sc < 8; ++sc)
    if (sc < n) {
      u16x4 v = *(const u16x4*)(Opart + ((base + sc) * 128 + tl) * 256 + c0);
      a0 += w[sc] * __uint_as_float((u32)v[0] << 16);
      a1 += w[sc] * __uint_as_float((u32)v[1] << 16);
      a2 += w[sc] * __uint_as_float((u32)v[2] << 16);
      a3 += w[sc] * __uint_as_float((u32)v[3] << 16);
    }
  f32x4 r; r[0] = a0 * inv; r[1] = a1 * inv; r[2] = a2 * inv; r[3] = a3 * inv;
  *(f32x4*)(out + (size_t)rg * 256 + c0) = r;
}

extern "C" void kernel_launch(void* const* d_in, const int* in_sizes, int n_in,
                              void* d_out, int out_size, void* d_ws, size_t ws_size,
                              hipStream_t stream) {
  const float* X  = (const float*)d_in[0];
  const float* Wq = (const float*)d_in[1];
  const float* bq = (const float*)d_in[2];
  const float* Wk = (const float*)d_in[3];
  const float* bk = (const float*)d_in[4];
  const float* Wv = (const float*)d_in[5];
  const float* bv = (const float*)d_in[6];
  float* out = (float*)d_out;
  char* ws = (char*)d_ws;

  const size_t OFF_WT  = 33554432;                       // [0, OFF_WT) free (reused as Opart tier B)
  const size_t OFF_Q   = OFF_WT + 1572864;               // Wt bf16 [3][256][1024]
  const size_t OFF_K   = OFF_Q + 8388608;                // Qb bf16 [16384][256] (pre-scaled 1/16)
  const size_t OFF_VT  = OFF_K + 8388608;                // Kb bf16 [16384][256]
  const size_t PREFIX  = OFF_VT + 8388608;               // Vtb bf16 [4][256][4096]  -> 60293120

  // tier A: s=3, gx=144 (QBLK=128). ML 4*144*128*8 = 589824; Opart 4*144*128*256*2 = 37748736.
  const size_t NEEDED_A = PREFIX + 589824 + 37748736;    // ~94.1 MiB (ws >= 132.7MB proven in r6)
  // tier B: s=4, gx=80. Opart 4*80*128*256*2 = 20971520 overlays dead region @0; ML 327680.
  const size_t NEEDED_B = PREFIX + 327680;               // ~57.8 MiB
  if (ws_size < NEEDED_B) return;                        // defensive: leave poison -> clear failure

  u16* Wt  = (u16*)(ws + OFF_WT);
  u16* Qb  = (u16*)(ws + OFF_Q);
  u16* Kb  = (u16*)(ws + OFF_K);
  u16* Vtb = (u16*)(ws + OFF_VT);

  int s, gx;
  u16* Opart;
  float2* ML;
  if (ws_size >= NEEDED_A) {                             // s=3: chunk 512, <=8 outer tiles/block
    s = 3; gx = 144;
    ML = (float2*)(ws + PREFIX);
    Opart = (u16*)(ws + PREFIX + 589824);
  } else {                                               // s=4: chunk 1024, <=16 outer tiles/block
    s = 4; gx = 80;
    ML = (float2*)(ws + PREFIX);
    Opart = (u16*)ws;                                    // overlays dead [0,21MB) region
  }

  cvt_w_kernel<<<3072, 256, 0, stream>>>(Wq, Wk, Wv, Wt);
  qkv_gemm_kernel<<<dim3(128, 2, 3), 256, 0, stream>>>(X, Wt, bq, bk, bv, Qb, Kb, Vtb);
  flash_kernel<<<4 * gx, 512, 0, stream>>>(Qb, Kb, Vtb, Opart, ML, s, gx);
  combine_kernel<<<4096, 256, 0, stream>>>(Opart, ML, out, s, gx);
}

// Round 14
// 159.791 us; speedup vs baseline: 1.2263x; 1.0519x over previous
//
#include <hip/hip_runtime.h>
#include <stdint.h>

typedef uint16_t u16;
typedef uint32_t u32;
typedef float    f32x4  __attribute__((ext_vector_type(4)));
typedef short    bf16x8 __attribute__((ext_vector_type(8)));   // 8 bf16 = 4 VGPR
typedef u32      u32x4  __attribute__((ext_vector_type(4)));
typedef u16      u16x8  __attribute__((ext_vector_type(8)));
typedef u16      u16x4  __attribute__((ext_vector_type(4)));

#define MFMA16(a, b, c) __builtin_amdgcn_mfma_f32_16x16x32_bf16((a), (b), (c), 0, 0, 0)

// D_MODEL=1024, D_K=256, B=4, T=4096, rows = B*T = 16384
// scores masked with -1e9 BEFORE /sqrt(d_k)=16 -> fold 1/16 into Q; mask = -1e30 logits (exp->0)
// Round 14 = r13 flash inner loop (unchanged) + two structure changes:
//  (a) LPT block ordering: non-diagonal (nto-full) blocks enumerate FIRST, diagonal blocks last
//      with qq descending -> the 64-block dispatch tail runs the SHORTEST blocks. Combine uses
//      the same slot bijection (contiguous non-diag run + one diag slot).
//  (b) qkv_gemm BN=256 (512 thr, 8 waves 2x4): X staged 3x instead of 6x -> L2/L3 traffic halved.

__device__ __forceinline__ u16 f2bf(float f) {           // fp32 -> bf16 RNE
  u32 x = __float_as_uint(f);
  return (u16)((x + 0x7FFFu + ((x >> 16) & 1u)) >> 16);
}

// Wt[m][n][k] = W_m[k][n]  (bf16, so GEMM B-frags read contiguous k)
__global__ __launch_bounds__(256) void cvt_w_kernel(const float* __restrict__ Wq,
                                                    const float* __restrict__ Wk,
                                                    const float* __restrict__ Wv,
                                                    u16* __restrict__ Wt) {
  int idx = blockIdx.x * 256 + threadIdx.x;              // < 786432
  int m = idx >> 18;
  int n = (idx >> 10) & 255;
  int k = idx & 1023;
  const float* W = (m == 0) ? Wq : (m == 1) ? Wk : Wv;
  Wt[idx] = f2bf(W[k * 256 + n]);
}

// C = X[16384x1024](f32, cvt in-reg) @ Wt^T + bias. BN=256: one block does ALL 256 cols of z.
// z=0: Q (pre-scaled 1/16), z=1: K, z=2: V stored transposed [B][256][4096].
__global__ __launch_bounds__(512) void qkv_gemm_kernel(
    const float* __restrict__ X, const u16* __restrict__ Wt,
    const float* __restrict__ bq, const float* __restrict__ bk, const float* __restrict__ bv,
    u16* __restrict__ Qb, u16* __restrict__ Kb, u16* __restrict__ Vtb) {
  __shared__ __align__(16) char sm[65536];               // Xs[128][64] @0 16KB, Ws[256][64] @16384 32KB
  const int tid = threadIdx.x;
  const int wid = tid >> 6, lane = tid & 63, g = lane >> 4, lr = lane & 15;
  const int wr = wid >> 2, wc = wid & 3;                 // 2 x 4 waves -> 64x64 output each
  const int m0 = blockIdx.x * 128, z = blockIdx.y;
  const u16* W = Wt + z * 262144;

  f32x4 acc[4][4];
#pragma unroll
  for (int mi = 0; mi < 4; ++mi)
#pragma unroll
    for (int ni = 0; ni < 4; ++ni) {
      acc[mi][ni][0] = 0.f; acc[mi][ni][1] = 0.f; acc[mi][ni][2] = 0.f; acc[mi][ni][3] = 0.f;
    }

  for (int k0 = 0; k0 < 1024; k0 += 64) {
    __syncthreads();
#pragma unroll
    for (int r = 0; r < 2; ++r) {                        // X: 1024 chunks, fused f32->bf16
      int ch = r * 512 + tid;
      int row = ch >> 3, c = ch & 7;
      const float* xp = X + (size_t)(m0 + row) * 1024 + k0 + c * 8;
      f32x4 xa = *(const f32x4*)xp;
      f32x4 xb = *(const f32x4*)(xp + 4);
      u16x8 xc;
      xc[0] = f2bf(xa[0]); xc[1] = f2bf(xa[1]); xc[2] = f2bf(xa[2]); xc[3] = f2bf(xa[3]);
      xc[4] = f2bf(xb[0]); xc[5] = f2bf(xb[1]); xc[6] = f2bf(xb[2]); xc[7] = f2bf(xb[3]);
      *(u16x8*)(sm + row * 128 + 16 * (c ^ (row & 7))) = xc;
    }
#pragma unroll
    for (int r = 0; r < 4; ++r) {                        // W: 2048 chunks (rows 0..255)
      int ch = r * 512 + tid;
      int row = ch >> 3, c = ch & 7;
      u32x4 vw = *(const u32x4*)(W + (size_t)row * 1024 + k0 + c * 8);
      *(u32x4*)(sm + 16384 + row * 128 + 16 * (c ^ (row & 7))) = vw;
    }
    __syncthreads();
#pragma unroll
    for (int kk = 0; kk < 2; ++kk) {
      bf16x8 af[4], bfr[4];
#pragma unroll
      for (int mi = 0; mi < 4; ++mi) {
        int row = wr * 64 + mi * 16 + lr;                // A-frag: lane holds row m=lane&15
        af[mi] = *(const bf16x8*)(sm + row * 128 + 16 * ((kk * 4 + g) ^ (row & 7)));
      }
#pragma unroll
      for (int ni = 0; ni < 4; ++ni) {
        int row = wc * 64 + ni * 16 + lr;                // B-frag: lane holds col n=lane&15
        bfr[ni] = *(const bf16x8*)(sm + 16384 + row * 128 + 16 * ((kk * 4 + g) ^ (row & 7)));
      }
#pragma unroll
      for (int mi = 0; mi < 4; ++mi)
#pragma unroll
        for (int ni = 0; ni < 4; ++ni)
          acc[mi][ni] = MFMA16(af[mi], bfr[ni], acc[mi][ni]);
    }
  }

  const float* bias = (z == 0) ? bq : (z == 1) ? bk : bv;
  if (z < 2) {
    u16* O = (z == 0) ? Qb : Kb;
    const float qscale = (z == 0) ? 0.0625f : 1.0f;      // fold 1/sqrt(256) into Q (exact in bf16)
#pragma unroll
    for (int ni = 0; ni < 4; ++ni) {
      int col = wc * 64 + ni * 16 + lr;
      float bb = bias[col];
#pragma unroll
      for (int mi = 0; mi < 4; ++mi)
#pragma unroll
        for (int j = 0; j < 4; ++j) {
          int row = m0 + wr * 64 + mi * 16 + 4 * g + j;  // C/D: col=lane&15, row=(lane>>4)*4+j
          O[(size_t)row * 256 + col] = f2bf((acc[mi][ni][j] + bb) * qscale);
        }
    }
  } else {
    // V transposed: stage bf16 tile [col 256][row 128] in LDS (64KB), then coalesced 16B stores
    __syncthreads();
#pragma unroll
    for (int ni = 0; ni < 4; ++ni) {
      int cl = wc * 64 + ni * 16 + lr;
      float bb = bias[cl];
#pragma unroll
      for (int mi = 0; mi < 4; ++mi)
#pragma unroll
        for (int j = 0; j < 4; ++j) {
          int rl = wr * 64 + mi * 16 + 4 * g + j;
          *(u16*)(sm + cl * 256 + rl * 2) = f2bf(acc[mi][ni][j] + bb);
        }
    }
    __syncthreads();
    int bidx = m0 >> 12, tb = m0 & 4095;                 // whole block is one batch
#pragma unroll
    for (int r = 0; r < 8; ++r) {
      int ch = r * 512 + tid;                            // 4096 chunks: 256 cols x 16 chunks
      int cl = ch >> 4, tp = ch & 15;
      u32x4 v = *(const u32x4*)(sm + cl * 256 + tp * 16);
      *(u32x4*)(Vtb + (size_t)bidx * 1048576 + (size_t)cl * 4096 + tb + tp * 8) = v;
    }
  }
}

// Split-KV flash: QBLK=128, 8 waves, swapped-QK^T in-reg softmax, KVBLK=64, T13, T14, LPT order.
// 1D grid 4*gx with XCD swizzle: xcd=bid&7 -> batch b=xcd>>1, i=(bid>>3)*2+(xcd&1).
// LPT enumeration: i<ND -> non-diagonal (nto = C/64, full); i>=ND -> diagonal, qq DESCENDING.
//   QG = 2^(s-1) qbs/group, NG = 32/QG groups; ND = QG*NG*(NG-1)/2.
//   non-diag: group gg has QG*gg blocks starting at QG*gg*(gg-1)/2; local -> qq=local/gg, sc=local%gg.
//   diag: j=i-ND; qq=QG-1-j/NG; gg=j%NG; sc=gg.
// LDS: K0@0,K1@16384 ([32 s][256 d], swz c^(srow&7)); V0@32768,V1@49152 ([256 d][32 s],
//      swz c2^((d>>1)&3)); P@65536 1KB/wave x8.
__global__ __launch_bounds__(512) void flash_kernel(
    const u16* __restrict__ Qb, const u16* __restrict__ Kb,
    const u16* __restrict__ Vtb, u16* __restrict__ Opart, float2* __restrict__ ML,
    int s, int gx) {
  __shared__ __align__(16) char sm[73728];
  const int tid = threadIdx.x, wid = tid >> 6, lane = tid & 63, g = lane >> 4, lr = lane & 15;
  const int xcd = blockIdx.x & 7;
  const int b = xcd >> 1;                                // batch pinned to XCD pair (L2 locality)
  const int i = ((blockIdx.x >> 3) << 1) + (xcd & 1);    // 0..gx-1, bijective (gx even)
  const int QG = 1 << (s - 1);
  const int NG = 32 >> (s - 1);
  const int ND = (QG * NG * (NG - 1)) >> 1;
  int gg, qq, sc;
  if (i < ND) {                                          // non-diagonal: full-length blocks first
    gg = 1;
    while (gg < NG - 1 && i >= ((QG * (gg + 1) * gg) >> 1)) ++gg;
    int local = i - ((QG * gg * (gg - 1)) >> 1);
    qq = local / gg;
    sc = local - qq * gg;                                // sc in [0, gg)
  } else {                                               // diagonal: qq descending (shortest last)
    int j = i - ND;
    int jd = j / NG;
    qq = (QG - 1) - jd;
    gg = j - jd * NG;
    sc = gg;
  }
  const int qb = gg * QG + qq;
  const int t0 = qb * 128;
  const int w0 = t0 + wid * 16;                          // this wave's 16 q-rows
  const int C = 64 << s;
  const int sbase = sc * C;                              // sbase <= t0 by construction

  bf16x8 qf[8];                                          // Q hoisted (already * 1/16); B-frag: col q=lr
  const u16* Qrow = Qb + (size_t)(b * 4096 + w0 + lr) * 256;
#pragma unroll
  for (int kk = 0; kk < 8; ++kk) qf[kk] = *(const bf16x8*)(Qrow + kk * 32 + g * 8);

  f32x4 o[16];                                           // o[n][j]: O[q=lr][dv=n*16+4g+j]
#pragma unroll
  for (int n = 0; n < 16; ++n) { o[n][0] = 0.f; o[n][1] = 0.f; o[n][2] = 0.f; o[n][3] = 0.f; }
  float m_ = -1e30f, l_ = 0.f;                           // per-lane: q-row = w0 + lr

  const u16* Kbase = Kb + (size_t)b * 4096 * 256;
  const u16* Vbase = Vtb + (size_t)b * 1048576;

  // T14 staging registers: next outer tile (K 64x256 + V 256x64) = 4+4 chunks of 16B per thread
  u32x4 pk[4], pv[4];
#define LOADTILE(os_)                                                                      \
  {                                                                                        \
    _Pragma("unroll")                                                                      \
    for (int q = 0; q < 4; ++q) {                                                          \
      int half = q >> 1, rr = q & 1;                                                       \
      int ch = rr * 512 + tid;                       /* 0..1023 within half-structure */   \
      int srow = ch >> 5, c = ch & 31;                                                     \
      pk[q] = *(const u32x4*)(Kbase + (size_t)((os_) + half * 32 + srow) * 256 + c * 8);   \
      int d = ch >> 2, c2 = ch & 3;                                                        \
      pv[q] = *(const u32x4*)(Vbase + (size_t)d * 4096 + (os_) + half * 32 + c2 * 8);      \
    }                                                                                      \
  }

  const int nto = min(C >> 6, (t0 + 128 - sbase) >> 6);  // OUTER tiles of 64 s-cols (>=1, exact)
  LOADTILE(sbase);                                       // prologue: tile 0 -> regs

  for (int ot = 0; ot < nto; ++ot) {
    const int os0 = sbase + ot * 64;
    __syncthreads();                                     // previous compute done -> LDS writable
#pragma unroll
    for (int q = 0; q < 4; ++q) {                        // reg -> LDS (layouts identical to r13)
      int half = q >> 1, rr = q & 1;
      int ch = rr * 512 + tid;
      int srow = ch >> 5, c = ch & 31;
      *(u32x4*)(sm + half * 16384 + srow * 512 + 16 * (c ^ (srow & 7))) = pk[q];
      int d = ch >> 2, c2 = ch & 3;
      *(u32x4*)(sm + 32768 + half * 16384 + d * 64 + 16 * (c2 ^ ((d >> 1) & 3))) = pv[q];
    }
    if (ot + 1 < nto) LOADTILE(os0 + 64);                // issue next tile; lands during compute
    __syncthreads();                                     // LDS ready

#pragma unroll 1
    for (int half = 0; half < 2; ++half) {               // two 32-col sub-tiles, no barrier between
      const int s0 = os0 + 32 * half;
      if (s0 > w0 + 15) break;                           // monotone: later sub-tiles masked too
      const char* kb = sm + half * 16384;
      const char* vb = sm + 32768 + half * 16384;

      // S^T = mfma(K_frag, Q_frag): C col=lane&15 = q (lr), row = 4g+j = s-within-16
      f32x4 sa[2];
#pragma unroll
      for (int ni = 0; ni < 2; ++ni) { sa[ni][0] = 0.f; sa[ni][1] = 0.f; sa[ni][2] = 0.f; sa[ni][3] = 0.f; }
#pragma unroll
      for (int ni = 0; ni < 2; ++ni) {
        int srw = ni * 16 + lr;                          // A-frag: lane holds row s_local = srw
#pragma unroll
        for (int kk = 0; kk < 8; ++kk) {
          bf16x8 kf = *(const bf16x8*)(kb + srw * 512 + 16 * ((kk * 4 + g) ^ (srw & 7)));
          sa[ni] = MFMA16(kf, qf[kk], sa[ni]);           // SWAPPED operands
        }
      }
      const int t = w0 + lr;                             // this lane's q-row
      if (s0 + 31 > w0) {                                // diagonal tile: mask t < s (logits, exp -> 0)
#pragma unroll
        for (int ni = 0; ni < 2; ++ni)
#pragma unroll
          for (int j = 0; j < 4; ++j) {
            int ss = s0 + ni * 16 + 4 * g + j;
            if (t < ss) sa[ni][j] = -1e30f;
          }
      }
      // in-register row softmax; partner lanes at xor 16/32 hold same q-row
      float mt = fmaxf(fmaxf(fmaxf(sa[0][0], sa[0][1]), fmaxf(sa[0][2], sa[0][3])),
                       fmaxf(fmaxf(sa[1][0], sa[1][1]), fmaxf(sa[1][2], sa[1][3])));
      mt = fmaxf(mt, __shfl_xor(mt, 16, 64));
      mt = fmaxf(mt, __shfl_xor(mt, 32, 64));
      // T13 defer-rescale: skip the O-wide rescale unless some row's max grew by > 8
      if (__any(mt > m_ + 8.0f)) {
        float mn = fmaxf(m_, mt);
        float scale = __expf(m_ - mn);
        m_ = mn;
        l_ *= scale;
#pragma unroll
        for (int n = 0; n < 16; ++n)
#pragma unroll
          for (int j = 0; j < 4; ++j) o[n][j] *= scale;
      }
#pragma unroll
      for (int ni = 0; ni < 2; ++ni)
#pragma unroll
        for (int j = 0; j < 4; ++j) sa[ni][j] = __expf(sa[ni][j] - m_);  // bounded by e^8
      float su = (sa[0][0] + sa[0][1]) + (sa[0][2] + sa[0][3]) +
                 (sa[1][0] + sa[1][1]) + (sa[1][2] + sa[1][3]);
      su += __shfl_xor(su, 16, 64);
      su += __shfl_xor(su, 32, 64);
      l_ += su;
      // P^T (bf16) -> per-wave swizzled LDS [q=lr][s chunks of 8], then read back as B-frag
#pragma unroll
      for (int ni = 0; ni < 2; ++ni)
#pragma unroll
        for (int j = 0; j < 4; ++j) {
          int c = ni * 2 + (g >> 1);                     // s = ni*16+4g+j -> chunk c, offset 4(g&1)+j
          *(u16*)(sm + 65536 + wid * 1024 + lr * 64 + 16 * (c ^ (lr & 3)) + (4 * (g & 1) + j) * 2) =
              f2bf(sa[ni][j]);
        }
      asm volatile("s_waitcnt lgkmcnt(0)" ::: "memory"); // cross-lane LDS visibility within wave
      bf16x8 pf = *(const bf16x8*)(sm + 65536 + wid * 1024 + lr * 64 + 16 * (g ^ (lr & 3)));
      // PV: O += mfma(V_frag, P^T_frag): A row dv-within-16, C col = q
#pragma unroll
      for (int n = 0; n < 16; ++n) {
        int d = n * 16 + lr;                             // A-frag: lane holds row dv = d
        bf16x8 vf = *(const bf16x8*)(vb + d * 64 + 16 * (g ^ ((d >> 1) & 3)));
        o[n] = MFMA16(vf, pf, o[n]);
      }
    }
  }
#undef LOADTILE

  // write UNNORMALIZED partial O (bf16) + (m,l) at compact slot = b*gx+i, LOCAL rows 0..127
  u16* Orow = Opart + ((size_t)(b * gx + i) * 128 + wid * 16) * 256;
#pragma unroll
  for (int n = 0; n < 16; ++n) {
    u16x4 pkk;
    pkk[0] = f2bf(o[n][0]); pkk[1] = f2bf(o[n][1]); pkk[2] = f2bf(o[n][2]); pkk[3] = f2bf(o[n][3]);
    *(u16x4*)(Orow + lr * 256 + n * 16 + 4 * g) = pkk;
  }
  if (lane < 16) {
    float2 ml; ml.x = m_; ml.y = l_;
    ML[(size_t)(b * gx + i) * 128 + wid * 16 + lane] = ml;
  }
}

// Merge splits (LPT slot mapping): row qb -> gg=qb>>(s-1), qq=qb&(QG-1); splits sc=0..gg.
// sc<gg at contiguous slots ibase+sc, sc==gg at idiag.
__global__ __launch_bounds__(256) void combine_kernel(const u16* __restrict__ Opart,
                                                      const float2* __restrict__ ML,
                                                      float* __restrict__ out,
                                                      int s, int gx) {
  const int wid = threadIdx.x >> 6, lane = threadIdx.x & 63;
  const int rg = blockIdx.x * 4 + wid;                   // 0..16383
  const int b = rg >> 12, t = rg & 4095;
  const int qb = t >> 7;                                 // 128-row slots
  const int QG = 1 << (s - 1), NG = 32 >> (s - 1);
  const int ND = (QG * NG * (NG - 1)) >> 1;
  const int gg = qb >> (s - 1), qq = qb & (QG - 1);
  const int n = gg + 1;                                  // valid splits (1..8)
  const int ibase = ((QG * gg * (gg - 1)) >> 1) + qq * gg;
  const int idiag = ND + (QG - 1 - qq) * NG + gg;
  const int tl = t & 127;                                // local row within slot
  int sl[8];
  float mv[8], lv[8], w[8];
  float M = -1e30f;
#pragma unroll
  for (int sc = 0; sc < 8; ++sc)
    if (sc < n) {
      sl[sc] = b * gx + ((sc < gg) ? (ibase + sc) : idiag);
      float2 ml = ML[(size_t)sl[sc] * 128 + tl];
      mv[sc] = ml.x; lv[sc] = ml.y;
      M = fmaxf(M, ml.x);
    }
  float L = 0.f;
#pragma unroll
  for (int sc = 0; sc < 8; ++sc)
    if (sc < n) { w[sc] = __expf(mv[sc] - M); L += w[sc] * lv[sc]; }
  const float inv = 1.0f / L;
  const int c0 = lane * 4;
  float a0 = 0.f, a1 = 0.f, a2 = 0.f, a3 = 0.f;
#pragma unroll
  for (int sc = 0; sc < 8; ++sc)
    if (sc < n) {
      u16x4 v = *(const u16x4*)(Opart + ((size_t)sl[sc] * 128 + tl) * 256 + c0);
      a0 += w[sc] * __uint_as_float((u32)v[0] << 16);
      a1 += w[sc] * __uint_as_float((u32)v[1] << 16);
      a2 += w[sc] * __uint_as_float((u32)v[2] << 16);
      a3 += w[sc] * __uint_as_float((u32)v[3] << 16);
    }
  f32x4 r; r[0] = a0 * inv; r[1] = a1 * inv; r[2] = a2 * inv; r[3] = a3 * inv;
  *(f32x4*)(out + (size_t)rg * 256 + c0) = r;
}

extern "C" void kernel_launch(void* const* d_in, const int* in_sizes, int n_in,
                              void* d_out, int out_size, void* d_ws, size_t ws_size,
                              hipStream_t stream) {
  const float* X  = (const float*)d_in[0];
  const float* Wq = (const float*)d_in[1];
  const float* bq = (const float*)d_in[2];
  const float* Wk = (const float*)d_in[3];
  const float* bk = (const float*)d_in[4];
  const float* Wv = (const float*)d_in[5];
  const float* bv = (const float*)d_in[6];
  float* out = (float*)d_out;
  char* ws = (char*)d_ws;

  const size_t OFF_WT  = 33554432;                       // [0, OFF_WT) free (reused as Opart tier B)
  const size_t OFF_Q   = OFF_WT + 1572864;               // Wt bf16 [3][256][1024]
  const size_t OFF_K   = OFF_Q + 8388608;                // Qb bf16 [16384][256] (pre-scaled 1/16)
  const size_t OFF_VT  = OFF_K + 8388608;                // Kb bf16 [16384][256]
  const size_t PREFIX  = OFF_VT + 8388608;               // Vtb bf16 [4][256][4096]  -> 60293120

  // tier A: s=3, gx=144 (QBLK=128). ML 4*144*128*8 = 589824; Opart 4*144*128*256*2 = 37748736.
  const size_t NEEDED_A = PREFIX + 589824 + 37748736;    // ~94.1 MiB (ws >= 132.7MB proven in r6)
  // tier B: s=4, gx=80. Opart 4*80*128*256*2 = 20971520 overlays dead region @0; ML 327680.
  const size_t NEEDED_B = PREFIX + 327680;               // ~57.8 MiB
  if (ws_size < NEEDED_B) return;                        // defensive: leave poison -> clear failure

  u16* Wt  = (u16*)(ws + OFF_WT);
  u16* Qb  = (u16*)(ws + OFF_Q);
  u16* Kb  = (u16*)(ws + OFF_K);
  u16* Vtb = (u16*)(ws + OFF_VT);

  int s, gx;
  u16* Opart;
  float2* ML;
  if (ws_size >= NEEDED_A) {                             // s=3: chunk 512, <=8 outer tiles/block
    s = 3; gx = 144;
    ML = (float2*)(ws + PREFIX);
    Opart = (u16*)(ws + PREFIX + 589824);
  } else {                                               // s=4: chunk 1024, <=16 outer tiles/block
    s = 4; gx = 80;
    ML = (float2*)(ws + PREFIX);
    Opart = (u16*)ws;                                    // overlays dead [0,21MB) region
  }

  cvt_w_kernel<<<3072, 256, 0, stream>>>(Wq, Wk, Wv, Wt);
  qkv_gemm_kernel<<<dim3(128, 3), 512, 0, stream>>>(X, Wt, bq, bk, bv, Qb, Kb, Vtb);
  flash_kernel<<<4 * gx, 512, 0, stream>>>(Qb, Kb, Vtb, Opart, ML, s, gx);
  combine_kernel<<<4096, 256, 0, stream>>>(Opart, ML, out, s, gx);
}

// Round 15
// 149.925 us; speedup vs baseline: 1.3070x; 1.0658x over previous
//
#include <hip/hip_runtime.h>
#include <stdint.h>

typedef uint16_t u16;
typedef uint32_t u32;
typedef float    f32x4  __attribute__((ext_vector_type(4)));
typedef short    bf16x8 __attribute__((ext_vector_type(8)));   // 8 bf16 = 4 VGPR
typedef u32      u32x4  __attribute__((ext_vector_type(4)));
typedef u32      u32x2  __attribute__((ext_vector_type(2)));
typedef u16      u16x8  __attribute__((ext_vector_type(8)));
typedef u16      u16x4  __attribute__((ext_vector_type(4)));

#define MFMA16(a, b, c) __builtin_amdgcn_mfma_f32_16x16x32_bf16((a), (b), (c), 0, 0, 0)

// D_MODEL=1024, D_K=256, B=4, T=4096, rows = B*T = 16384
// scores masked with -1e9 BEFORE /sqrt(d_k)=16 -> fold 1/16 into Q; mask = -1e30 logits (exp->0)
// Round 15 = r14 flash (82us) + P-store packing (8 u16 -> 2 ds_write_b64; j=0..3 are contiguous
// bytes 8(g&1)+{0,2,4,6} in one 16B slot) + qkv_gemm REVERTED to r13 (BN=128, 256thr, grid 768:
// r14's BN=256 cost ~10us -- 384-block grid tail; X was L3-resident so traffic saving was moot).

__device__ __forceinline__ u16 f2bf(float f) {           // fp32 -> bf16 RNE
  u32 x = __float_as_uint(f);
  return (u16)((x + 0x7FFFu + ((x >> 16) & 1u)) >> 16);
}

// Wt[m][n][k] = W_m[k][n]  (bf16, so GEMM B-frags read contiguous k)
__global__ __launch_bounds__(256) void cvt_w_kernel(const float* __restrict__ Wq,
                                                    const float* __restrict__ Wk,
                                                    const float* __restrict__ Wv,
                                                    u16* __restrict__ Wt) {
  int idx = blockIdx.x * 256 + threadIdx.x;              // < 786432
  int m = idx >> 18;
  int n = (idx >> 10) & 255;
  int k = idx & 1023;
  const float* W = (m == 0) ? Wq : (m == 1) ? Wk : Wv;
  Wt[idx] = f2bf(W[k * 256 + n]);
}

// C = X[16384x1024](f32, cvt in-reg) @ Wt^T + bias. z=0: Q (pre-scaled 1/16), z=1: K,
// z=2: V stored transposed [B][256][4096].  (r13-proven version)
__global__ __launch_bounds__(256) void qkv_gemm_kernel(
    const float* __restrict__ X, const u16* __restrict__ Wt,
    const float* __restrict__ bq, const float* __restrict__ bk, const float* __restrict__ bv,
    u16* __restrict__ Qb, u16* __restrict__ Kb, u16* __restrict__ Vtb) {
  __shared__ __align__(16) char sm[32768];               // Xs [128][64]bf16 @0, Ws [128][64]bf16 @16384
  const int tid = threadIdx.x;
  const int wid = tid >> 6, lane = tid & 63, g = lane >> 4, lr = lane & 15;
  const int wr = wid >> 1, wc = wid & 1;
  const int m0 = blockIdx.x * 128, n0 = blockIdx.y * 128, z = blockIdx.z;
  const u16* W = Wt + z * 262144;

  f32x4 acc[4][4];
#pragma unroll
  for (int mi = 0; mi < 4; ++mi)
#pragma unroll
    for (int ni = 0; ni < 4; ++ni) {
      acc[mi][ni][0] = 0.f; acc[mi][ni][1] = 0.f; acc[mi][ni][2] = 0.f; acc[mi][ni][3] = 0.f;
    }

  for (int k0 = 0; k0 < 1024; k0 += 64) {
    __syncthreads();
#pragma unroll
    for (int r = 0; r < 4; ++r) {
      int ch = r * 256 + tid;
      int row = ch >> 3, c = ch & 7;
      const float* xp = X + (size_t)(m0 + row) * 1024 + k0 + c * 8;   // fused cvt_x
      f32x4 xa = *(const f32x4*)xp;
      f32x4 xb = *(const f32x4*)(xp + 4);
      u16x8 xc;
      xc[0] = f2bf(xa[0]); xc[1] = f2bf(xa[1]); xc[2] = f2bf(xa[2]); xc[3] = f2bf(xa[3]);
      xc[4] = f2bf(xb[0]); xc[5] = f2bf(xb[1]); xc[6] = f2bf(xb[2]); xc[7] = f2bf(xb[3]);
      *(u16x8*)(sm + row * 128 + 16 * (c ^ (row & 7))) = xc;
      u32x4 vw = *(const u32x4*)(W + (size_t)(n0 + row) * 1024 + k0 + c * 8);
      *(u32x4*)(sm + 16384 + row * 128 + 16 * (c ^ (row & 7))) = vw;
    }
    __syncthreads();
#pragma unroll
    for (int kk = 0; kk < 2; ++kk) {
      bf16x8 af[4], bfr[4];
#pragma unroll
      for (int mi = 0; mi < 4; ++mi) {
        int row = wr * 64 + mi * 16 + lr;                // A-frag: lane holds row m=lane&15
        af[mi] = *(const bf16x8*)(sm + row * 128 + 16 * ((kk * 4 + g) ^ (row & 7)));
      }
#pragma unroll
      for (int ni = 0; ni < 4; ++ni) {
        int row = wc * 64 + ni * 16 + lr;                // B-frag: lane holds col n=lane&15
        bfr[ni] = *(const bf16x8*)(sm + 16384 + row * 128 + 16 * ((kk * 4 + g) ^ (row & 7)));
      }
#pragma unroll
      for (int mi = 0; mi < 4; ++mi)
#pragma unroll
        for (int ni = 0; ni < 4; ++ni)
          acc[mi][ni] = MFMA16(af[mi], bfr[ni], acc[mi][ni]);
    }
  }

  const float* bias = (z == 0) ? bq : (z == 1) ? bk : bv;
  if (z < 2) {
    u16* O = (z == 0) ? Qb : Kb;
    const float qscale = (z == 0) ? 0.0625f : 1.0f;      // fold 1/sqrt(256) into Q (exact in bf16)
#pragma unroll
    for (int ni = 0; ni < 4; ++ni) {
      int col = n0 + wc * 64 + ni * 16 + lr;
      float bb = bias[col];
#pragma unroll
      for (int mi = 0; mi < 4; ++mi)
#pragma unroll
        for (int j = 0; j < 4; ++j) {
          int row = m0 + wr * 64 + mi * 16 + 4 * g + j;  // C/D: col=lane&15, row=(lane>>4)*4+j
          O[(size_t)row * 256 + col] = f2bf((acc[mi][ni][j] + bb) * qscale);
        }
    }
  } else {
    // V transposed: stage bf16 tile [col 128][row 128] in LDS, then coalesced 16B stores
    __syncthreads();
#pragma unroll
    for (int ni = 0; ni < 4; ++ni) {
      int cl = wc * 64 + ni * 16 + lr;
      float bb = bias[n0 + cl];
#pragma unroll
      for (int mi = 0; mi < 4; ++mi)
#pragma unroll
        for (int j = 0; j < 4; ++j) {
          int rl = wr * 64 + mi * 16 + 4 * g + j;
          *(u16*)(sm + cl * 256 + rl * 2) = f2bf(acc[mi][ni][j] + bb);
        }
    }
    __syncthreads();
    int bidx = m0 >> 12, tb = m0 & 4095;                 // whole block is one batch (m0 % 128 == 0)
#pragma unroll
    for (int r = 0; r < 8; ++r) {
      int ch = r * 256 + tid;                            // 2048 chunks of 16B: 128 cols x 16 chunks
      int cl = ch >> 4, tp = ch & 15;
      u32x4 v = *(const u32x4*)(sm + cl * 256 + tp * 16);
      *(u32x4*)(Vtb + (size_t)bidx * 1048576 + (size_t)(n0 + cl) * 4096 + tb + tp * 8) = v;
    }
  }
}

// Split-KV flash: QBLK=128, 8 waves, swapped-QK^T in-reg softmax, KVBLK=64, T13, T14, LPT order.
// 1D grid 4*gx with XCD swizzle: xcd=bid&7 -> batch b=xcd>>1, i=(bid>>3)*2+(xcd&1).
// LPT enumeration: i<ND -> non-diagonal (full-length); i>=ND -> diagonal, qq DESCENDING.
// LDS: K0@0,K1@16384 ([32 s][256 d], swz c^(srow&7)); V0@32768,V1@49152 ([256 d][32 s],
//      swz c2^((d>>1)&3)); P@65536 1KB/wave x8.
__global__ __launch_bounds__(512) void flash_kernel(
    const u16* __restrict__ Qb, const u16* __restrict__ Kb,
    const u16* __restrict__ Vtb, u16* __restrict__ Opart, float2* __restrict__ ML,
    int s, int gx) {
  __shared__ __align__(16) char sm[73728];
  const int tid = threadIdx.x, wid = tid >> 6, lane = tid & 63, g = lane >> 4, lr = lane & 15;
  const int xcd = blockIdx.x & 7;
  const int b = xcd >> 1;                                // batch pinned to XCD pair (L2 locality)
  const int i = ((blockIdx.x >> 3) << 1) + (xcd & 1);    // 0..gx-1, bijective (gx even)
  const int QG = 1 << (s - 1);
  const int NG = 32 >> (s - 1);
  const int ND = (QG * NG * (NG - 1)) >> 1;
  int gg, qq, sc;
  if (i < ND) {                                          // non-diagonal: full-length blocks first
    gg = 1;
    while (gg < NG - 1 && i >= ((QG * (gg + 1) * gg) >> 1)) ++gg;
    int local = i - ((QG * gg * (gg - 1)) >> 1);
    qq = local / gg;
    sc = local - qq * gg;                                // sc in [0, gg)
  } else {                                               // diagonal: qq descending (shortest last)
    int j = i - ND;
    int jd = j / NG;
    qq = (QG - 1) - jd;
    gg = j - jd * NG;
    sc = gg;
  }
  const int qb = gg * QG + qq;
  const int t0 = qb * 128;
  const int w0 = t0 + wid * 16;                          // this wave's 16 q-rows
  const int C = 64 << s;
  const int sbase = sc * C;                              // sbase <= t0 by construction

  bf16x8 qf[8];                                          // Q hoisted (already * 1/16); B-frag: col q=lr
  const u16* Qrow = Qb + (size_t)(b * 4096 + w0 + lr) * 256;
#pragma unroll
  for (int kk = 0; kk < 8; ++kk) qf[kk] = *(const bf16x8*)(Qrow + kk * 32 + g * 8);

  f32x4 o[16];                                           // o[n][j]: O[q=lr][dv=n*16+4g+j]
#pragma unroll
  for (int n = 0; n < 16; ++n) { o[n][0] = 0.f; o[n][1] = 0.f; o[n][2] = 0.f; o[n][3] = 0.f; }
  float m_ = -1e30f, l_ = 0.f;                           // per-lane: q-row = w0 + lr

  const u16* Kbase = Kb + (size_t)b * 4096 * 256;
  const u16* Vbase = Vtb + (size_t)b * 1048576;

  // T14 staging registers: next outer tile (K 64x256 + V 256x64) = 4+4 chunks of 16B per thread
  u32x4 pk[4], pv[4];
#define LOADTILE(os_)                                                                      \
  {                                                                                        \
    _Pragma("unroll")                                                                      \
    for (int q = 0; q < 4; ++q) {                                                          \
      int half = q >> 1, rr = q & 1;                                                       \
      int ch = rr * 512 + tid;                       /* 0..1023 within half-structure */   \
      int srow = ch >> 5, c = ch & 31;                                                     \
      pk[q] = *(const u32x4*)(Kbase + (size_t)((os_) + half * 32 + srow) * 256 + c * 8);   \
      int d = ch >> 2, c2 = ch & 3;                                                        \
      pv[q] = *(const u32x4*)(Vbase + (size_t)d * 4096 + (os_) + half * 32 + c2 * 8);      \
    }                                                                                      \
  }

  const int nto = min(C >> 6, (t0 + 128 - sbase) >> 6);  // OUTER tiles of 64 s-cols (>=1, exact)
  LOADTILE(sbase);                                       // prologue: tile 0 -> regs

  for (int ot = 0; ot < nto; ++ot) {
    const int os0 = sbase + ot * 64;
    __syncthreads();                                     // previous compute done -> LDS writable
#pragma unroll
    for (int q = 0; q < 4; ++q) {                        // reg -> LDS (layouts identical to r14)
      int half = q >> 1, rr = q & 1;
      int ch = rr * 512 + tid;
      int srow = ch >> 5, c = ch & 31;
      *(u32x4*)(sm + half * 16384 + srow * 512 + 16 * (c ^ (srow & 7))) = pk[q];
      int d = ch >> 2, c2 = ch & 3;
      *(u32x4*)(sm + 32768 + half * 16384 + d * 64 + 16 * (c2 ^ ((d >> 1) & 3))) = pv[q];
    }
    if (ot + 1 < nto) LOADTILE(os0 + 64);                // issue next tile; lands during compute
    __syncthreads();                                     // LDS ready

#pragma unroll 1
    for (int half = 0; half < 2; ++half) {               // two 32-col sub-tiles, no barrier between
      const int s0 = os0 + 32 * half;
      if (s0 > w0 + 15) break;                           // monotone: later sub-tiles masked too
      const char* kb = sm + half * 16384;
      const char* vb = sm + 32768 + half * 16384;

      // S^T = mfma(K_frag, Q_frag): C col=lane&15 = q (lr), row = 4g+j = s-within-16
      f32x4 sa[2];
#pragma unroll
      for (int ni = 0; ni < 2; ++ni) { sa[ni][0] = 0.f; sa[ni][1] = 0.f; sa[ni][2] = 0.f; sa[ni][3] = 0.f; }
#pragma unroll
      for (int ni = 0; ni < 2; ++ni) {
        int srw = ni * 16 + lr;                          // A-frag: lane holds row s_local = srw
#pragma unroll
        for (int kk = 0; kk < 8; ++kk) {
          bf16x8 kf = *(const bf16x8*)(kb + srw * 512 + 16 * ((kk * 4 + g) ^ (srw & 7)));
          sa[ni] = MFMA16(kf, qf[kk], sa[ni]);           // SWAPPED operands
        }
      }
      const int t = w0 + lr;                             // this lane's q-row
      if (s0 + 31 > w0) {                                // diagonal tile: mask t < s (logits, exp -> 0)
#pragma unroll
        for (int ni = 0; ni < 2; ++ni)
#pragma unroll
          for (int j = 0; j < 4; ++j) {
            int ss = s0 + ni * 16 + 4 * g + j;
            if (t < ss) sa[ni][j] = -1e30f;
          }
      }
      // in-register row softmax; partner lanes at xor 16/32 hold same q-row
      float mt = fmaxf(fmaxf(fmaxf(sa[0][0], sa[0][1]), fmaxf(sa[0][2], sa[0][3])),
                       fmaxf(fmaxf(sa[1][0], sa[1][1]), fmaxf(sa[1][2], sa[1][3])));
      mt = fmaxf(mt, __shfl_xor(mt, 16, 64));
      mt = fmaxf(mt, __shfl_xor(mt, 32, 64));
      // T13 defer-rescale: skip the O-wide rescale unless some row's max grew by > 8
      if (__any(mt > m_ + 8.0f)) {
        float mn = fmaxf(m_, mt);
        float scale = __expf(m_ - mn);
        m_ = mn;
        l_ *= scale;
#pragma unroll
        for (int n = 0; n < 16; ++n)
#pragma unroll
          for (int j = 0; j < 4; ++j) o[n][j] *= scale;
      }
#pragma unroll
      for (int ni = 0; ni < 2; ++ni)
#pragma unroll
        for (int j = 0; j < 4; ++j) sa[ni][j] = __expf(sa[ni][j] - m_);  // bounded by e^8
      float su = (sa[0][0] + sa[0][1]) + (sa[0][2] + sa[0][3]) +
                 (sa[1][0] + sa[1][1]) + (sa[1][2] + sa[1][3]);
      su += __shfl_xor(su, 16, 64);
      su += __shfl_xor(su, 32, 64);
      l_ += su;
      // P^T (bf16) -> per-wave swizzled LDS. j=0..3 land at contiguous bytes 8(g&1)+{0,2,4,6}
      // within slot c^(lr&3): pack to ONE ds_write_b64 per ni (was 4 u16 stores).
#pragma unroll
      for (int ni = 0; ni < 2; ++ni) {
        int c = ni * 2 + (g >> 1);
        u32x2 pw;
        pw[0] = (u32)f2bf(sa[ni][0]) | ((u32)f2bf(sa[ni][1]) << 16);
        pw[1] = (u32)f2bf(sa[ni][2]) | ((u32)f2bf(sa[ni][3]) << 16);
        *(u32x2*)(sm + 65536 + wid * 1024 + lr * 64 + 16 * (c ^ (lr & 3)) + 8 * (g & 1)) = pw;
      }
      asm volatile("s_waitcnt lgkmcnt(0)" ::: "memory"); // cross-lane LDS visibility within wave
      bf16x8 pf = *(const bf16x8*)(sm + 65536 + wid * 1024 + lr * 64 + 16 * (g ^ (lr & 3)));
      // PV: O += mfma(V_frag, P^T_frag): A row dv-within-16, C col = q
#pragma unroll
      for (int n = 0; n < 16; ++n) {
        int d = n * 16 + lr;                             // A-frag: lane holds row dv = d
        bf16x8 vf = *(const bf16x8*)(vb + d * 64 + 16 * (g ^ ((d >> 1) & 3)));
        o[n] = MFMA16(vf, pf, o[n]);
      }
    }
  }
#undef LOADTILE

  // write UNNORMALIZED partial O (bf16) + (m,l) at compact slot = b*gx+i, LOCAL rows 0..127
  u16* Orow = Opart + ((size_t)(b * gx + i) * 128 + wid * 16) * 256;
#pragma unroll
  for (int n = 0; n < 16; ++n) {
    u16x4 pkk;
    pkk[0] = f2bf(o[n][0]); pkk[1] = f2bf(o[n][1]); pkk[2] = f2bf(o[n][2]); pkk[3] = f2bf(o[n][3]);
    *(u16x4*)(Orow + lr * 256 + n * 16 + 4 * g) = pkk;
  }
  if (lane < 16) {
    float2 ml; ml.x = m_; ml.y = l_;
    ML[(size_t)(b * gx + i) * 128 + wid * 16 + lane] = ml;
  }
}

// Merge splits (LPT slot mapping): row qb -> gg=qb>>(s-1), qq=qb&(QG-1); splits sc=0..gg.
// sc<gg at contiguous slots ibase+sc, sc==gg at idiag.
__global__ __launch_bounds__(256) void combine_kernel(const u16* __restrict__ Opart,
                                                      const float2* __restrict__ ML,
                                                      float* __restrict__ out,
                                                      int s, int gx) {
  const int wid = threadIdx.x >> 6, lane = threadIdx.x & 63;
  const int rg = blockIdx.x * 4 + wid;                   // 0..16383
  const int b = rg >> 12, t = rg & 4095;
  const int qb = t >> 7;                                 // 128-row slots
  const int QG = 1 << (s - 1), NG = 32 >> (s - 1);
  const int ND = (QG * NG * (NG - 1)) >> 1;
  const int gg = qb >> (s - 1), qq = qb & (QG - 1);
  const int n = gg + 1;                                  // valid splits (1..8)
  const int ibase = ((QG * gg * (gg - 1)) >> 1) + qq * gg;
  const int idiag = ND + (QG - 1 - qq) * NG + gg;
  const int tl = t & 127;                                // local row within slot
  int sl[8];
  float mv[8], lv[8], w[8];
  float M = -1e30f;
#pragma unroll
  for (int sc = 0; sc < 8; ++sc)
    if (sc < n) {
      sl[sc] = b * gx + ((sc < gg) ? (ibase + sc) : idiag);
      float2 ml = ML[(size_t)sl[sc] * 128 + tl];
      mv[sc] = ml.x; lv[sc] = ml.y;
      M = fmaxf(M, ml.x);
    }
  float L = 0.f;
#pragma unroll
  for (int sc = 0; sc < 8; ++sc)
    if (sc < n) { w[sc] = __expf(mv[sc] - M); L += w[sc] * lv[sc]; }
  const float inv = 1.0f / L;
  const int c0 = lane * 4;
  float a0 = 0.f, a1 = 0.f, a2 = 0.f, a3 = 0.f;
#pragma unroll
  for (int sc = 0; sc < 8; ++sc)
    if (sc < n) {
      u16x4 v = *(const u16x4*)(Opart + ((size_t)sl[sc] * 128 + tl) * 256 + c0);
      a0 += w[sc] * __uint_as_float((u32)v[0] << 16);
      a1 += w[sc] * __uint_as_float((u32)v[1] << 16);
      a2 += w[sc] * __uint_as_float((u32)v[2] << 16);
      a3 += w[sc] * __uint_as_float((u32)v[3] << 16);
    }
  f32x4 r; r[0] = a0 * inv; r[1] = a1 * inv; r[2] = a2 * inv; r[3] = a3 * inv;
  *(f32x4*)(out + (size_t)rg * 256 + c0) = r;
}

extern "C" void kernel_launch(void* const* d_in, const int* in_sizes, int n_in,
                              void* d_out, int out_size, void* d_ws, size_t ws_size,
                              hipStream_t stream) {
  const float* X  = (const float*)d_in[0];
  const float* Wq = (const float*)d_in[1];
  const float* bq = (const float*)d_in[2];
  const float* Wk = (const float*)d_in[3];
  const float* bk = (const float*)d_in[4];
  const float* Wv = (const float*)d_in[5];
  const float* bv = (const float*)d_in[6];
  float* out = (float*)d_out;
  char* ws = (char*)d_ws;

  const size_t OFF_WT  = 33554432;                       // [0, OFF_WT) free (reused as Opart tier B)
  const size_t OFF_Q   = OFF_WT + 1572864;               // Wt bf16 [3][256][1024]
  const size_t OFF_K   = OFF_Q + 8388608;                // Qb bf16 [16384][256] (pre-scaled 1/16)
  const size_t OFF_VT  = OFF_K + 8388608;                // Kb bf16 [16384][256]
  const size_t PREFIX  = OFF_VT + 8388608;               // Vtb bf16 [4][256][4096]  -> 60293120

  // tier A: s=3, gx=144 (QBLK=128). ML 4*144*128*8 = 589824; Opart 4*144*128*256*2 = 37748736.
  const size_t NEEDED_A = PREFIX + 589824 + 37748736;    // ~94.1 MiB (ws >= 132.7MB proven in r6)
  // tier B: s=4, gx=80. Opart 4*80*128*256*2 = 20971520 overlays dead region @0; ML 327680.
  const size_t NEEDED_B = PREFIX + 327680;               // ~57.8 MiB
  if (ws_size < NEEDED_B) return;                        // defensive: leave poison -> clear failure

  u16* Wt  = (u16*)(ws + OFF_WT);
  u16* Qb  = (u16*)(ws + OFF_Q);
  u16* Kb  = (u16*)(ws + OFF_K);
  u16* Vtb = (u16*)(ws + OFF_VT);

  int s, gx;
  u16* Opart;
  float2* ML;
  if (ws_size >= NEEDED_A) {                             // s=3: chunk 512, <=8 outer tiles/block
    s = 3; gx = 144;
    ML = (float2*)(ws + PREFIX);
    Opart = (u16*)(ws + PREFIX + 589824);
  } else {                                               // s=4: chunk 1024, <=16 outer tiles/block
    s = 4; gx = 80;
    ML = (float2*)(ws + PREFIX);
    Opart = (u16*)ws;                                    // overlays dead [0,21MB) region
  }

  cvt_w_kernel<<<3072, 256, 0, stream>>>(Wq, Wk, Wv, Wt);
  qkv_gemm_kernel<<<dim3(128, 2, 3), 256, 0, stream>>>(X, Wt, bq, bk, bv, Qb, Kb, Vtb);
  flash_kernel<<<4 * gx, 512, 0, stream>>>(Qb, Kb, Vtb, Opart, ML, s, gx);
  combine_kernel<<<4096, 256, 0, stream>>>(Opart, ML, out, s, gx);
}